// Round 4
// baseline (818.499 us; speedup 1.0000x reference)
//
#include <hip/hip_runtime.h>
#include <math.h>
#include <stdint.h>

#define N_PIX 4096
#define CDIM 256
#define DINNER 512
#define HEADS 8
#define DHEAD 64

typedef float vf4 __attribute__((ext_vector_type(4)));
typedef float f32x4 __attribute__((ext_vector_type(4)));
typedef _Float16 half8 __attribute__((ext_vector_type(8)));
typedef _Float16 half4v __attribute__((ext_vector_type(4)));

// log2(e) scalings: softmax done in exp2 domain
#define LOG2E 1.44269504f
#define CKSQ_SCALE 0.18033688f   /* 0.125 * log2e */
#define C1 0.36067376f           /* 0.25  * log2e */

// ---------------------------------------------------------------------------
// Kernel 1: per-pixel channel L2 norm -> rnorm = sqrt(256)/max(||x||,1e-12)
// ---------------------------------------------------------------------------
__global__ __launch_bounds__(256) void rnorm_kernel(const float* __restrict__ fmap,
                                                    float* __restrict__ rnorm) {
    __shared__ float red[4][64];
    const int t = threadIdx.x;
    const int pl = t & 63;
    const int part = t >> 6;
    const int pix0 = blockIdx.x * 64;
    const int gp = pix0 + pl;
    const int b = gp >> 12, p = gp & 4095;
    const float* f = fmap + ((size_t)b * CDIM + part * 64) * N_PIX + p;
    float s = 0.f;
    #pragma unroll 8
    for (int c = 0; c < 64; ++c) { float x = f[(size_t)c * N_PIX]; s = fmaf(x, x, s); }
    red[part][pl] = s;
    __syncthreads();
    if (t < 64) {
        float tot = red[0][t] + red[1][t] + red[2][t] + red[3][t];
        rnorm[pix0 + t] = 16.0f / fmaxf(sqrtf(tot), 1e-12f);
    }
}

// ---------------------------------------------------------------------------
// Kernel 2: projection GEMM -> fp16 Qh [bh][p][64], fp16 Vh [bh][64][p-perm],
// cksq [bh][p] = 0.125*log2e*sum_d qh^2 (from ROUNDED fp16 q -> diag max exact).
// V stored with per-64 j-permutation: storage s = kv*32+g*8+e holds
// j = kv*32 + (e>>2)*16 + g*4 + (e&3), so attn V-frags are single 16B loads.
// ---------------------------------------------------------------------------
__global__ __launch_bounds__(256) void proj_kernel(
    const float* __restrict__ fmap, const float* __restrict__ gamma,
    const float* __restrict__ Wq, const float* __restrict__ Wv,
    const float* __restrict__ rnorm,
    _Float16* __restrict__ Qh, _Float16* __restrict__ Vh,
    float* __restrict__ cksq) {
    const int pt = blockIdx.x, mt = blockIdx.y, b = blockIdx.z;
    const int p0 = pt * 64, m0 = mt * 64;
    const bool isQ = (m0 < DINNER);
    const float* W = isQ ? Wq : Wv;
    const int or0 = isQ ? m0 : m0 - DINNER;
    const int h = or0 >> 6;           // head
    const int bh = b * 8 + h;

    __shared__ float As[16][68];
    __shared__ float Bs[16][68];
    const int t = threadIdx.x, tm = t >> 4, tn = t & 15;
    float acc[4][4] = {};

    for (int kt = 0; kt < CDIM; kt += 16) {
        __syncthreads();
        for (int e = t; e < 1024; e += 256) {
            int m = e >> 4, kk = e & 15;
            As[kk][m] = W[(size_t)(or0 + m) * CDIM + kt + kk] * gamma[kt + kk];
        }
        for (int e = t; e < 1024; e += 256) {
            int kk = e >> 6, pp = e & 63;
            Bs[kk][pp] = fmap[((size_t)b * CDIM + kt + kk) * N_PIX + p0 + pp];
        }
        __syncthreads();
        #pragma unroll
        for (int kk = 0; kk < 16; ++kk) {
            vf4 a = *(const vf4*)&As[kk][4 * tm];
            vf4 bb = *(const vf4*)&Bs[kk][4 * tn];
            #pragma unroll
            for (int r = 0; r < 4; ++r)
                #pragma unroll
                for (int c = 0; c < 4; ++c)
                    acc[r][c] = fmaf(a[r], bb[c], acc[r][c]);
        }
    }

    // apply rnorm, round to fp16
    _Float16 hq[4][4];
    float part[4] = {0.f, 0.f, 0.f, 0.f};
    #pragma unroll
    for (int c = 0; c < 4; ++c) {
        float rn = rnorm[b * N_PIX + p0 + 4 * tn + c];
        #pragma unroll
        for (int r = 0; r < 4; ++r) {
            _Float16 hv = (_Float16)(acc[r][c] * rn);
            hq[r][c] = hv;
            float qrf = (float)hv;
            part[c] = fmaf(qrf, qrf, part[c]);
        }
    }

    if (isQ) {
        // Qh[bh][p][d]
        #pragma unroll
        for (int c = 0; c < 4; ++c) {
            half4v hv = {hq[0][c], hq[1][c], hq[2][c], hq[3][c]};
            *(half4v*)(Qh + ((size_t)bh * N_PIX + p0 + 4 * tn + c) * 64 + 4 * tm) = hv;
        }
        // reduce per-pixel ksq over the 16 tm groups via LDS (reuse Bs)
        __syncthreads();
        *(vf4*)&Bs[tm][4 * tn] = vf4{part[0], part[1], part[2], part[3]};
        __syncthreads();
        if (t < 64) {
            float s = 0.f;
            #pragma unroll
            for (int r = 0; r < 16; ++r) s += Bs[r][t];
            cksq[(size_t)bh * N_PIX + p0 + t] = CKSQ_SCALE * s;
        }
    } else {
        // Vh[bh][d][j-permuted]: j = 4*tn + c -> s = kv*32 + g*8 + hi*4 + c
        const int kv = tn >> 3, gg = tn & 3, hi = (tn >> 2) & 1;
        const int sb = kv * 32 + gg * 8 + hi * 4;
        #pragma unroll
        for (int r = 0; r < 4; ++r) {
            half4v hv = {hq[r][0], hq[r][1], hq[r][2], hq[r][3]};
            *(half4v*)(Vh + ((size_t)bh * 64 + 4 * tm + r) * N_PIX + p0 + sb) = hv;
        }
    }
}

// ---------------------------------------------------------------------------
// Kernel 3: fp16 MFMA flash attention via SWAPPED QK^T (S^T = mfma(K, Q)).
// k = q; null kv analytic; m_i = max(0.125*qsq_i, nullsim_i) known upfront.
// Block = 4 waves: pair = w>>1 selects 32-row group, jhalf = w&1 splits the
// KV range (32 tiles each); partial (l, O) combined through LDS at the end.
// Grid 1024 -> 16 waves/CU demanded.
// ---------------------------------------------------------------------------
__global__ __launch_bounds__(256, 4) void attn_kernel(
    const _Float16* __restrict__ Qh,   // [bh][p][64]
    const _Float16* __restrict__ Vh,   // [bh][64][p-perm]
    const float* __restrict__ cksq,    // [bh][p] = 0.125*log2e*ksq
    const float* __restrict__ nullkv,  // [2][8][64] fp32
    float* __restrict__ AO)            // [b][512][p]
{
    const int n = blockIdx.x;
    const int idx = n >> 3;
    const int bh = (n & 7) * 2 + (idx >> 6);   // XCD swizzle: 2 bh per XCD
    const int it = idx & 63;
    const int h = bh & 7;

    __shared__ float ksq_lds[4096];
    __shared__ f32x4 xo[2][2][4][64];   // [pair][s][dt][lane]
    __shared__ float xl[2][2][64];      // [pair][s][lane]

    const int t = threadIdx.x;
    const int w = t >> 6;
    const int lane = t & 63;
    const int col = lane & 15;
    const int g = lane >> 4;
    const int pair = w >> 1;
    const int jhalf = w & 1;

    const float* ck = cksq + (size_t)bh * N_PIX;
    for (int e = t; e < 4096; e += 256) ksq_lds[e] = ck[e];
    __syncthreads();

    const int i0 = it * 64 + pair * 32;
    const _Float16* qbase = Qh + (size_t)bh * N_PIX * 64;
    const _Float16* vbase = Vh + (size_t)bh * 64 * N_PIX;

    // Q fragments (B-operand of S^T mfma): row = l&15, k-map d = dk*32+g*8+e
    half8 qf[2][2];
    #pragma unroll
    for (int s = 0; s < 2; ++s)
        #pragma unroll
        for (int dk = 0; dk < 2; ++dk)
            qf[s][dk] = *(const half8*)(qbase + ((size_t)(i0 + s * 16 + col)) * 64 + dk * 32 + g * 8);

    // null kv: per-lane nd for q-row = l&15 after g-group reduction
    float nkv[2][8];
    #pragma unroll
    for (int dk = 0; dk < 2; ++dk) {
        const float* np = nullkv + h * 64 + dk * 32 + g * 8;
        vf4 a = *(const vf4*)np;
        vf4 b2 = *(const vf4*)(np + 4);
        nkv[dk][0] = a[0]; nkv[dk][1] = a[1]; nkv[dk][2] = a[2]; nkv[dk][3] = a[3];
        nkv[dk][4] = b2[0]; nkv[dk][5] = b2[1]; nkv[dk][6] = b2[2]; nkv[dk][7] = b2[3];
    }
    float nd0 = 0.f, nd1 = 0.f, nkk = 0.f;
    #pragma unroll
    for (int dk = 0; dk < 2; ++dk)
        #pragma unroll
        for (int e = 0; e < 8; ++e) {
            float nkval = nkv[dk][e];
            nkk = fmaf(nkval, nkval, nkk);
            nd0 = fmaf((float)qf[0][dk][e], nkval, nd0);
            nd1 = fmaf((float)qf[1][dk][e], nkval, nd1);
        }
    nd0 += __shfl_xor(nd0, 16); nd0 += __shfl_xor(nd0, 32);
    nd1 += __shfl_xor(nd1, 16); nd1 += __shfl_xor(nd1, 32);
    nkk += __shfl_xor(nkk, 16); nkk += __shfl_xor(nkk, 32);

    // null V values at d = dt*16 + 4g + r (matches O^T D-layout)
    vf4 nv4[4];
    #pragma unroll
    for (int dt = 0; dt < 4; ++dt)
        nv4[dt] = *(const vf4*)(nullkv + DINNER + h * 64 + dt * 16 + 4 * g);

    float m_[2], l_[2];
    f32x4 oaccT[2][4];
    #pragma unroll
    for (int s = 0; s < 2; ++s) {
        float ndv = (s == 0) ? nd0 : nd1;
        float nsim = fmaf(0.25f, ndv, -0.125f * nkk) * LOG2E;
        float ci = ksq_lds[i0 + s * 16 + col];
        float m = fmaxf(ci, nsim);
        m_[s] = m;
        if (jhalf == 0) {
            float wn = exp2f(nsim - m);
            l_[s] = wn * 0.25f;           // null l split across the 4 g-lanes
            #pragma unroll
            for (int dt = 0; dt < 4; ++dt)
                #pragma unroll
                for (int r = 0; r < 4; ++r)
                    oaccT[s][dt][r] = wn * nv4[dt][r];
        } else {
            l_[s] = 0.f;
            #pragma unroll
            for (int dt = 0; dt < 4; ++dt)
                oaccT[s][dt] = f32x4{0.f, 0.f, 0.f, 0.f};
        }
    }

    const int jt0 = jhalf * 32;
    for (int jj = 0; jj < 32; ++jj) {
        const int j0 = (jt0 + jj) * 64;
        // K fragments (A-operand, k = q): row = l&15, same k-map as Q
        half8 kf[4][2];
        #pragma unroll
        for (int jt = 0; jt < 4; ++jt)
            #pragma unroll
            for (int dk = 0; dk < 2; ++dk)
                kf[jt][dk] = *(const half8*)(qbase + (size_t)(j0 + jt * 16 + col) * 64 + dk * 32 + g * 8);
        // V fragments (A-operand of PV): one 16B load each (permuted layout)
        half8 vfr[2][4];
        #pragma unroll
        for (int kv = 0; kv < 2; ++kv)
            #pragma unroll
            for (int dt = 0; dt < 4; ++dt)
                vfr[kv][dt] = *(const half8*)(vbase + (size_t)(dt * 16 + col) * N_PIX + j0 + kv * 32 + g * 8);
        // ksq (log2-scaled) for this lane's j values: j = jt*16 + 4g + r
        vf4 cj[4];
        #pragma unroll
        for (int jt = 0; jt < 4; ++jt)
            cj[jt] = *(const vf4*)&ksq_lds[j0 + jt * 16 + 4 * g];

        #pragma unroll
        for (int s = 0; s < 2; ++s) {
            // S^T: D[row = k-row 4g+r][col = q-row l&15]
            f32x4 sfT[4];
            __builtin_amdgcn_s_setprio(1);
            #pragma unroll
            for (int jt = 0; jt < 4; ++jt) {
                sfT[jt] = f32x4{0.f, 0.f, 0.f, 0.f};
                #pragma unroll
                for (int dk = 0; dk < 2; ++dk)
                    sfT[jt] = __builtin_amdgcn_mfma_f32_16x16x32_f16(kf[jt][dk], qf[s][dk], sfT[jt], 0, 0, 0);
            }
            __builtin_amdgcn_s_setprio(0);
            // softmax in exp2 domain: m fixed (diag max), i = l&15 per lane
            const float m = m_[s];
            float pv[4][4];
            float lp0 = 0.f, lp1 = 0.f;
            #pragma unroll
            for (int jt = 0; jt < 4; ++jt)
                #pragma unroll
                for (int r = 0; r < 4; ++r) {
                    float p = exp2f(fmaf(C1, sfT[jt][r], -cj[jt][r] - m));
                    pv[jt][r] = p;
                    if (jt < 2) lp0 += p; else lp1 += p;
                }
            l_[s] += lp0 + lp1;
            half8 pf0 = {(_Float16)pv[0][0], (_Float16)pv[0][1], (_Float16)pv[0][2], (_Float16)pv[0][3],
                         (_Float16)pv[1][0], (_Float16)pv[1][1], (_Float16)pv[1][2], (_Float16)pv[1][3]};
            half8 pf1 = {(_Float16)pv[2][0], (_Float16)pv[2][1], (_Float16)pv[2][2], (_Float16)pv[2][3],
                         (_Float16)pv[3][0], (_Float16)pv[3][1], (_Float16)pv[3][2], (_Float16)pv[3][3]};
            // O^T[d][i] += sum_j V[d][j] * P[i][j]
            __builtin_amdgcn_s_setprio(1);
            #pragma unroll
            for (int dt = 0; dt < 4; ++dt) {
                oaccT[s][dt] = __builtin_amdgcn_mfma_f32_16x16x32_f16(vfr[0][dt], pf0, oaccT[s][dt], 0, 0, 0);
                oaccT[s][dt] = __builtin_amdgcn_mfma_f32_16x16x32_f16(vfr[1][dt], pf1, oaccT[s][dt], 0, 0, 0);
            }
            __builtin_amdgcn_s_setprio(0);
        }
    }

    // pair-combine: odd (jhalf=1) wave publishes partials; even wave reduces,
    // normalizes and stores.
    __syncthreads();
    if (jhalf) {
        #pragma unroll
        for (int s = 0; s < 2; ++s) {
            xl[pair][s][lane] = l_[s];
            #pragma unroll
            for (int dt = 0; dt < 4; ++dt)
                xo[pair][s][dt][lane] = oaccT[s][dt];
        }
    }
    __syncthreads();
    if (!jhalf) {
        float* aob = AO + ((size_t)(bh >> 3) * DINNER + h * 64) * N_PIX;
        #pragma unroll
        for (int s = 0; s < 2; ++s) {
            float l = l_[s] + xl[pair][s][lane];
            l += __shfl_xor(l, 16); l += __shfl_xor(l, 32);
            float linv = 1.f / l;
            const int p = i0 + s * 16 + col;
            #pragma unroll
            for (int dt = 0; dt < 4; ++dt) {
                f32x4 o = oaccT[s][dt] + xo[pair][s][dt][lane];
                #pragma unroll
                for (int r = 0; r < 4; ++r)
                    aob[(size_t)(dt * 16 + 4 * g + r) * N_PIX + p] = o[r] * linv;
            }
        }
    }
}

// ---------------------------------------------------------------------------
// Kernel 4: output GEMM  out[o=256][p] = sum_c Wout[o][c] * AO[b][c][p]
// ---------------------------------------------------------------------------
__global__ __launch_bounds__(256) void outproj_kernel(
    const float* __restrict__ AO, const float* __restrict__ Wout,
    float* __restrict__ out) {
    const int pt = blockIdx.x, mt = blockIdx.y, b = blockIdx.z;
    const int p0 = pt * 64, m0 = mt * 64;
    __shared__ float As[16][68];
    __shared__ float Bs[16][68];
    const int t = threadIdx.x, tm = t >> 4, tn = t & 15;
    float acc[4][4] = {};
    for (int kt = 0; kt < DINNER; kt += 16) {
        __syncthreads();
        for (int e = t; e < 1024; e += 256) {
            int m = e >> 4, kk = e & 15;
            As[kk][m] = Wout[(size_t)(m0 + m) * DINNER + kt + kk];
        }
        for (int e = t; e < 1024; e += 256) {
            int kk = e >> 6, pp = e & 63;
            Bs[kk][pp] = AO[((size_t)b * DINNER + kt + kk) * N_PIX + p0 + pp];
        }
        __syncthreads();
        #pragma unroll
        for (int kk = 0; kk < 16; ++kk) {
            vf4 a = *(const vf4*)&As[kk][4 * tm];
            vf4 bb = *(const vf4*)&Bs[kk][4 * tn];
            #pragma unroll
            for (int r = 0; r < 4; ++r)
                #pragma unroll
                for (int c = 0; c < 4; ++c)
                    acc[r][c] = fmaf(a[r], bb[c], acc[r][c]);
        }
    }
    #pragma unroll
    for (int r = 0; r < 4; ++r) {
        vf4 o4 = {acc[r][0], acc[r][1], acc[r][2], acc[r][3]};
        *(vf4*)&out[((size_t)b * CDIM + m0 + 4 * tm + r) * N_PIX + p0 + 4 * tn] = o4;
    }
}

// ---------------------------------------------------------------------------
extern "C" void kernel_launch(void* const* d_in, const int* in_sizes, int n_in,
                              void* d_out, int out_size, void* d_ws, size_t ws_size,
                              hipStream_t stream) {
    const float* fmap   = (const float*)d_in[0];
    const float* gamma  = (const float*)d_in[1];
    const float* Wq     = (const float*)d_in[2];
    const float* Wv     = (const float*)d_in[3];
    const float* Wout   = (const float*)d_in[4];
    const float* nullkv = (const float*)d_in[5];
    float* out = (float*)d_out;

    char* wsb = (char*)d_ws;
    _Float16* Qh  = (_Float16*)wsb;                          // 8 MB
    _Float16* Vh  = (_Float16*)(wsb + (8u << 20));           // 8 MB
    float*    AO  = (float*)(wsb + (16u << 20));             // 16 MB
    float*    cksq = (float*)(wsb + (32u << 20));            // 256 KB
    float*    rnorm = (float*)(wsb + (33u << 20));           // 32 KB

    rnorm_kernel<<<128, 256, 0, stream>>>(fmap, rnorm);
    proj_kernel<<<dim3(64, 16, 2), 256, 0, stream>>>(fmap, gamma, Wq, Wv, rnorm, Qh, Vh, cksq);
    attn_kernel<<<1024, 256, 0, stream>>>(Qh, Vh, cksq, nullkv, AO);
    outproj_kernel<<<dim3(64, 4, 2), 256, 0, stream>>>(AO, Wout, out);
}

// Round 5
// 599.667 us; speedup vs baseline: 1.3649x; 1.3649x over previous
//
#include <hip/hip_runtime.h>
#include <math.h>
#include <stdint.h>

#define N_PIX 4096
#define CDIM 256
#define DINNER 512
#define HEADS 8
#define DHEAD 64

typedef float vf4 __attribute__((ext_vector_type(4)));
typedef float f32x4 __attribute__((ext_vector_type(4)));
typedef _Float16 half8 __attribute__((ext_vector_type(8)));
typedef _Float16 half4v __attribute__((ext_vector_type(4)));

// log2(e) scalings: softmax done in exp2 domain
#define LOG2E 1.44269504f
#define CKSQ_SCALE 0.18033688f   /* 0.125 * log2e */
#define C1 0.36067376f           /* 0.25  * log2e */

// ---------------------------------------------------------------------------
// Kernel 1: per-pixel channel L2 norm -> rnorm = sqrt(256)/max(||x||,1e-12)
// ---------------------------------------------------------------------------
__global__ __launch_bounds__(256) void rnorm_kernel(const float* __restrict__ fmap,
                                                    float* __restrict__ rnorm) {
    __shared__ float red[4][64];
    const int t = threadIdx.x;
    const int pl = t & 63;
    const int part = t >> 6;
    const int pix0 = blockIdx.x * 64;
    const int gp = pix0 + pl;
    const int b = gp >> 12, p = gp & 4095;
    const float* f = fmap + ((size_t)b * CDIM + part * 64) * N_PIX + p;
    float s = 0.f;
    #pragma unroll 8
    for (int c = 0; c < 64; ++c) { float x = f[(size_t)c * N_PIX]; s = fmaf(x, x, s); }
    red[part][pl] = s;
    __syncthreads();
    if (t < 64) {
        float tot = red[0][t] + red[1][t] + red[2][t] + red[3][t];
        rnorm[pix0 + t] = 16.0f / fmaxf(sqrtf(tot), 1e-12f);
    }
}

// ---------------------------------------------------------------------------
// Kernel 2: projection GEMM -> fp16 Qh [bh][p][64], fp16 Vh [bh][64][p-perm],
// cksq [bh][p] = 0.125*log2e*sum_d qh^2 (from ROUNDED fp16 q -> diag max exact).
// V stored with per-64 j-permutation so attn V-frags are single 16B loads.
// ---------------------------------------------------------------------------
__global__ __launch_bounds__(256) void proj_kernel(
    const float* __restrict__ fmap, const float* __restrict__ gamma,
    const float* __restrict__ Wq, const float* __restrict__ Wv,
    const float* __restrict__ rnorm,
    _Float16* __restrict__ Qh, _Float16* __restrict__ Vh,
    float* __restrict__ cksq) {
    const int pt = blockIdx.x, mt = blockIdx.y, b = blockIdx.z;
    const int p0 = pt * 64, m0 = mt * 64;
    const bool isQ = (m0 < DINNER);
    const float* W = isQ ? Wq : Wv;
    const int or0 = isQ ? m0 : m0 - DINNER;
    const int h = or0 >> 6;           // head
    const int bh = b * 8 + h;

    __shared__ float As[16][68];
    __shared__ float Bs[16][68];
    const int t = threadIdx.x, tm = t >> 4, tn = t & 15;
    float acc[4][4] = {};

    for (int kt = 0; kt < CDIM; kt += 16) {
        __syncthreads();
        for (int e = t; e < 1024; e += 256) {
            int m = e >> 4, kk = e & 15;
            As[kk][m] = W[(size_t)(or0 + m) * CDIM + kt + kk] * gamma[kt + kk];
        }
        for (int e = t; e < 1024; e += 256) {
            int kk = e >> 6, pp = e & 63;
            Bs[kk][pp] = fmap[((size_t)b * CDIM + kt + kk) * N_PIX + p0 + pp];
        }
        __syncthreads();
        #pragma unroll
        for (int kk = 0; kk < 16; ++kk) {
            vf4 a = *(const vf4*)&As[kk][4 * tm];
            vf4 bb = *(const vf4*)&Bs[kk][4 * tn];
            #pragma unroll
            for (int r = 0; r < 4; ++r)
                #pragma unroll
                for (int c = 0; c < 4; ++c)
                    acc[r][c] = fmaf(a[r], bb[c], acc[r][c]);
        }
    }

    // apply rnorm, round to fp16
    _Float16 hq[4][4];
    float part[4] = {0.f, 0.f, 0.f, 0.f};
    #pragma unroll
    for (int c = 0; c < 4; ++c) {
        float rn = rnorm[b * N_PIX + p0 + 4 * tn + c];
        #pragma unroll
        for (int r = 0; r < 4; ++r) {
            _Float16 hv = (_Float16)(acc[r][c] * rn);
            hq[r][c] = hv;
            float qrf = (float)hv;
            part[c] = fmaf(qrf, qrf, part[c]);
        }
    }

    if (isQ) {
        // Qh[bh][p][d]
        #pragma unroll
        for (int c = 0; c < 4; ++c) {
            half4v hv = {hq[0][c], hq[1][c], hq[2][c], hq[3][c]};
            *(half4v*)(Qh + ((size_t)bh * N_PIX + p0 + 4 * tn + c) * 64 + 4 * tm) = hv;
        }
        // reduce per-pixel ksq over the 16 tm groups via LDS (reuse Bs)
        __syncthreads();
        *(vf4*)&Bs[tm][4 * tn] = vf4{part[0], part[1], part[2], part[3]};
        __syncthreads();
        if (t < 64) {
            float s = 0.f;
            #pragma unroll
            for (int r = 0; r < 16; ++r) s += Bs[r][t];
            cksq[(size_t)bh * N_PIX + p0 + t] = CKSQ_SCALE * s;
        }
    } else {
        // Vh[bh][d][j-permuted]: j = 4*tn + c -> s = kv*32 + g*8 + hi*4 + c
        const int kv = tn >> 3, gg = tn & 3, hi = (tn >> 2) & 1;
        const int sb = kv * 32 + gg * 8 + hi * 4;
        #pragma unroll
        for (int r = 0; r < 4; ++r) {
            half4v hv = {hq[r][0], hq[r][1], hq[r][2], hq[r][3]};
            *(half4v*)(Vh + ((size_t)bh * 64 + 4 * tm + r) * N_PIX + p0 + sb) = hv;
        }
    }
}

// ---------------------------------------------------------------------------
// Kernel 3: fp16 MFMA flash attention via SWAPPED QK^T (S^T = mfma(K, Q)).
// Round-3 structure (4 waves x 32 rows, full KV per wave, (256,2)) plus
// register ping-pong double-buffer of the K/V fragments: tile j+1's 16
// global loads are issued before tile j's compute, so L2/L3 latency hides
// under the MFMA+exp2 phase (T14 mechanism, register-staged).
// ---------------------------------------------------------------------------
__device__ __forceinline__ void load_kv(const _Float16* __restrict__ qbase,
                                        const _Float16* __restrict__ vbase,
                                        int j0, int col, int g,
                                        half8 (&kf)[4][2], half8 (&vf)[2][4]) {
    #pragma unroll
    for (int jt = 0; jt < 4; ++jt)
        #pragma unroll
        for (int dk = 0; dk < 2; ++dk)
            kf[jt][dk] = *(const half8*)(qbase + (size_t)(j0 + jt * 16 + col) * 64 + dk * 32 + g * 8);
    #pragma unroll
    for (int kv = 0; kv < 2; ++kv)
        #pragma unroll
        for (int dt = 0; dt < 4; ++dt)
            vf[kv][dt] = *(const half8*)(vbase + (size_t)(dt * 16 + col) * N_PIX + j0 + kv * 32 + g * 8);
}

__device__ __forceinline__ void step_tile(const half8 (&kf)[4][2], const half8 (&vf)[2][4],
                                          const half8 (&qf)[2][2], const float (&m_)[2],
                                          float (&l_)[2], f32x4 (&oaccT)[2][4],
                                          const float (&ksq_lds)[4096], int j0, int g) {
    vf4 cj[4];
    #pragma unroll
    for (int jt = 0; jt < 4; ++jt)
        cj[jt] = *(const vf4*)&ksq_lds[j0 + jt * 16 + 4 * g];

    #pragma unroll
    for (int s = 0; s < 2; ++s) {
        // S^T: D[row = k-row 4g+r][col = q-row l&15]
        f32x4 sfT[4];
        __builtin_amdgcn_s_setprio(1);
        #pragma unroll
        for (int jt = 0; jt < 4; ++jt) {
            sfT[jt] = f32x4{0.f, 0.f, 0.f, 0.f};
            #pragma unroll
            for (int dk = 0; dk < 2; ++dk)
                sfT[jt] = __builtin_amdgcn_mfma_f32_16x16x32_f16(kf[jt][dk], qf[s][dk], sfT[jt], 0, 0, 0);
        }
        __builtin_amdgcn_s_setprio(0);
        // softmax in exp2 domain: m fixed (diag max), i = l&15 per lane
        const float m = m_[s];
        float pv[4][4];
        float lp0 = 0.f, lp1 = 0.f;
        #pragma unroll
        for (int jt = 0; jt < 4; ++jt)
            #pragma unroll
            for (int r = 0; r < 4; ++r) {
                float p = exp2f(fmaf(C1, sfT[jt][r], -cj[jt][r] - m));
                pv[jt][r] = p;
                if (jt < 2) lp0 += p; else lp1 += p;
            }
        l_[s] += lp0 + lp1;
        half8 pf0 = {(_Float16)pv[0][0], (_Float16)pv[0][1], (_Float16)pv[0][2], (_Float16)pv[0][3],
                     (_Float16)pv[1][0], (_Float16)pv[1][1], (_Float16)pv[1][2], (_Float16)pv[1][3]};
        half8 pf1 = {(_Float16)pv[2][0], (_Float16)pv[2][1], (_Float16)pv[2][2], (_Float16)pv[2][3],
                     (_Float16)pv[3][0], (_Float16)pv[3][1], (_Float16)pv[3][2], (_Float16)pv[3][3]};
        // O^T[d][i] += sum_j V[d][j] * P[i][j]
        __builtin_amdgcn_s_setprio(1);
        #pragma unroll
        for (int dt = 0; dt < 4; ++dt) {
            oaccT[s][dt] = __builtin_amdgcn_mfma_f32_16x16x32_f16(vf[0][dt], pf0, oaccT[s][dt], 0, 0, 0);
            oaccT[s][dt] = __builtin_amdgcn_mfma_f32_16x16x32_f16(vf[1][dt], pf1, oaccT[s][dt], 0, 0, 0);
        }
        __builtin_amdgcn_s_setprio(0);
    }
}

__global__ __launch_bounds__(256, 2) void attn_kernel(
    const _Float16* __restrict__ Qh,   // [bh][p][64]
    const _Float16* __restrict__ Vh,   // [bh][64][p-perm]
    const float* __restrict__ cksq,    // [bh][p] = 0.125*log2e*ksq
    const float* __restrict__ nullkv,  // [2][8][64] fp32
    float* __restrict__ AO)            // [b][512][p]
{
    const int n = blockIdx.x;
    const int slot = n >> 3;
    const int bh = (n & 7) * 2 + (slot >> 5);   // XCD swizzle: 2 bh per XCD
    const int it = slot & 31;
    const int h = bh & 7;

    __shared__ float ksq_lds[4096];

    const int t = threadIdx.x;
    const int w = t >> 6;
    const int lane = t & 63;
    const int col = lane & 15;
    const int g = lane >> 4;

    const float* ck = cksq + (size_t)bh * N_PIX;
    for (int e = t; e < 4096; e += 256) ksq_lds[e] = ck[e];
    __syncthreads();

    const int i0 = it * 128 + w * 32;
    const _Float16* qbase = Qh + (size_t)bh * N_PIX * 64;
    const _Float16* vbase = Vh + (size_t)bh * 64 * N_PIX;

    // Q fragments (B-operand of S^T mfma): row = l&15, k-map d = dk*32+g*8+e
    half8 qf[2][2];
    #pragma unroll
    for (int s = 0; s < 2; ++s)
        #pragma unroll
        for (int dk = 0; dk < 2; ++dk)
            qf[s][dk] = *(const half8*)(qbase + ((size_t)(i0 + s * 16 + col)) * 64 + dk * 32 + g * 8);

    // null kv: per-lane nd for q-row = l&15 after g-group reduction
    float nkv[2][8];
    #pragma unroll
    for (int dk = 0; dk < 2; ++dk) {
        const float* np = nullkv + h * 64 + dk * 32 + g * 8;
        vf4 a = *(const vf4*)np;
        vf4 b2 = *(const vf4*)(np + 4);
        nkv[dk][0] = a[0]; nkv[dk][1] = a[1]; nkv[dk][2] = a[2]; nkv[dk][3] = a[3];
        nkv[dk][4] = b2[0]; nkv[dk][5] = b2[1]; nkv[dk][6] = b2[2]; nkv[dk][7] = b2[3];
    }
    float nd0 = 0.f, nd1 = 0.f, nkk = 0.f;
    #pragma unroll
    for (int dk = 0; dk < 2; ++dk)
        #pragma unroll
        for (int e = 0; e < 8; ++e) {
            float nkval = nkv[dk][e];
            nkk = fmaf(nkval, nkval, nkk);
            nd0 = fmaf((float)qf[0][dk][e], nkval, nd0);
            nd1 = fmaf((float)qf[1][dk][e], nkval, nd1);
        }
    nd0 += __shfl_xor(nd0, 16); nd0 += __shfl_xor(nd0, 32);
    nd1 += __shfl_xor(nd1, 16); nd1 += __shfl_xor(nd1, 32);
    nkk += __shfl_xor(nkk, 16); nkk += __shfl_xor(nkk, 32);

    // null V values at d = dt*16 + 4g + r (matches O^T D-layout)
    vf4 nv4[4];
    #pragma unroll
    for (int dt = 0; dt < 4; ++dt)
        nv4[dt] = *(const vf4*)(nullkv + DINNER + h * 64 + dt * 16 + 4 * g);

    float m_[2], l_[2];
    f32x4 oaccT[2][4];
    #pragma unroll
    for (int s = 0; s < 2; ++s) {
        float ndv = (s == 0) ? nd0 : nd1;
        float nsim = fmaf(0.25f, ndv, -0.125f * nkk) * LOG2E;
        float ci = ksq_lds[i0 + s * 16 + col];
        float m = fmaxf(ci, nsim);
        m_[s] = m;
        float wn = exp2f(nsim - m);
        l_[s] = wn * 0.25f;               // null l split across the 4 g-lanes
        #pragma unroll
        for (int dt = 0; dt < 4; ++dt)
            #pragma unroll
            for (int r = 0; r < 4; ++r)
                oaccT[s][dt][r] = wn * nv4[dt][r];
    }

    // ping-pong register double-buffer over the 64 KV tiles
    half8 kfA[4][2], vfA[2][4], kfB[4][2], vfB[2][4];
    load_kv(qbase, vbase, 0, col, g, kfA, vfA);
    #pragma unroll 1
    for (int jj = 0; jj < 64; jj += 2) {
        load_kv(qbase, vbase, (jj + 1) * 64, col, g, kfB, vfB);
        step_tile(kfA, vfA, qf, m_, l_, oaccT, ksq_lds, jj * 64, g);
        load_kv(qbase, vbase, ((jj + 2) & 63) * 64, col, g, kfA, vfA);
        step_tile(kfB, vfB, qf, m_, l_, oaccT, ksq_lds, (jj + 1) * 64, g);
    }

    // epilogue: reduce l over the 4 g-lanes, normalize, store
    float* aob = AO + ((size_t)(bh >> 3) * DINNER + h * 64) * N_PIX;
    #pragma unroll
    for (int s = 0; s < 2; ++s) {
        float l = l_[s];
        l += __shfl_xor(l, 16); l += __shfl_xor(l, 32);
        float linv = 1.f / l;
        const int p = i0 + s * 16 + col;
        #pragma unroll
        for (int dt = 0; dt < 4; ++dt)
            #pragma unroll
            for (int r = 0; r < 4; ++r)
                aob[(size_t)(dt * 16 + 4 * g + r) * N_PIX + p] = oaccT[s][dt][r] * linv;
    }
}

// ---------------------------------------------------------------------------
// Kernel 4: output GEMM  out[o=256][p] = sum_c Wout[o][c] * AO[b][c][p]
// ---------------------------------------------------------------------------
__global__ __launch_bounds__(256) void outproj_kernel(
    const float* __restrict__ AO, const float* __restrict__ Wout,
    float* __restrict__ out) {
    const int pt = blockIdx.x, mt = blockIdx.y, b = blockIdx.z;
    const int p0 = pt * 64, m0 = mt * 64;
    __shared__ float As[16][68];
    __shared__ float Bs[16][68];
    const int t = threadIdx.x, tm = t >> 4, tn = t & 15;
    float acc[4][4] = {};
    for (int kt = 0; kt < DINNER; kt += 16) {
        __syncthreads();
        for (int e = t; e < 1024; e += 256) {
            int m = e >> 4, kk = e & 15;
            As[kk][m] = Wout[(size_t)(m0 + m) * DINNER + kt + kk];
        }
        for (int e = t; e < 1024; e += 256) {
            int kk = e >> 6, pp = e & 63;
            Bs[kk][pp] = AO[((size_t)b * DINNER + kt + kk) * N_PIX + p0 + pp];
        }
        __syncthreads();
        #pragma unroll
        for (int kk = 0; kk < 16; ++kk) {
            vf4 a = *(const vf4*)&As[kk][4 * tm];
            vf4 bb = *(const vf4*)&Bs[kk][4 * tn];
            #pragma unroll
            for (int r = 0; r < 4; ++r)
                #pragma unroll
                for (int c = 0; c < 4; ++c)
                    acc[r][c] = fmaf(a[r], bb[c], acc[r][c]);
        }
    }
    #pragma unroll
    for (int r = 0; r < 4; ++r) {
        vf4 o4 = {acc[r][0], acc[r][1], acc[r][2], acc[r][3]};
        *(vf4*)&out[((size_t)b * CDIM + m0 + 4 * tm + r) * N_PIX + p0 + 4 * tn] = o4;
    }
}

// ---------------------------------------------------------------------------
extern "C" void kernel_launch(void* const* d_in, const int* in_sizes, int n_in,
                              void* d_out, int out_size, void* d_ws, size_t ws_size,
                              hipStream_t stream) {
    const float* fmap   = (const float*)d_in[0];
    const float* gamma  = (const float*)d_in[1];
    const float* Wq     = (const float*)d_in[2];
    const float* Wv     = (const float*)d_in[3];
    const float* Wout   = (const float*)d_in[4];
    const float* nullkv = (const float*)d_in[5];
    float* out = (float*)d_out;

    char* wsb = (char*)d_ws;
    _Float16* Qh  = (_Float16*)wsb;                          // 8 MB
    _Float16* Vh  = (_Float16*)(wsb + (8u << 20));           // 8 MB
    float*    AO  = (float*)(wsb + (16u << 20));             // 16 MB
    float*    cksq = (float*)(wsb + (32u << 20));            // 256 KB
    float*    rnorm = (float*)(wsb + (33u << 20));           // 32 KB

    rnorm_kernel<<<128, 256, 0, stream>>>(fmap, rnorm);
    proj_kernel<<<dim3(64, 16, 2), 256, 0, stream>>>(fmap, gamma, Wq, Wv, rnorm, Qh, Vh, cksq);
    attn_kernel<<<512, 256, 0, stream>>>(Qh, Vh, cksq, nullkv, AO);
    outproj_kernel<<<dim3(64, 4, 2), 256, 0, stream>>>(AO, Wout, out);
}

// Round 6
// 288.511 us; speedup vs baseline: 2.8370x; 2.0785x over previous
//
#include <hip/hip_runtime.h>
#include <math.h>
#include <stdint.h>

#define N_PIX 4096
#define CDIM 256
#define DINNER 512

typedef float vf4 __attribute__((ext_vector_type(4)));
typedef float f32x4 __attribute__((ext_vector_type(4)));
typedef _Float16 half8 __attribute__((ext_vector_type(8)));
typedef _Float16 half4v __attribute__((ext_vector_type(4)));

// log2(e) scalings: softmax done in exp2 domain
#define LOG2E 1.44269504f
#define CKSQ_SCALE 0.18033688f   /* 0.125 * log2e */
#define C1 0.36067376f           /* 0.25  * log2e */

// async global->LDS, 16B per lane, LDS dest = wave-uniform base + lane*16
#define GLOAD_LDS16(g, l)                                                  \
    __builtin_amdgcn_global_load_lds(                                      \
        (const __attribute__((address_space(1))) unsigned int*)(g),       \
        (__attribute__((address_space(3))) unsigned int*)(l), 16, 0, 0)

// ---------------------------------------------------------------------------
// Kernel 1: per-pixel channel L2 norm -> rnorm = sqrt(256)/max(||x||,1e-12)
// ---------------------------------------------------------------------------
__global__ __launch_bounds__(256) void rnorm_kernel(const float* __restrict__ fmap,
                                                    float* __restrict__ rnorm) {
    __shared__ float red[4][64];
    const int t = threadIdx.x;
    const int pl = t & 63;
    const int part = t >> 6;
    const int pix0 = blockIdx.x * 64;
    const int gp = pix0 + pl;
    const int b = gp >> 12, p = gp & 4095;
    const float* f = fmap + ((size_t)b * CDIM + part * 64) * N_PIX + p;
    float s = 0.f;
    #pragma unroll 8
    for (int c = 0; c < 64; ++c) { float x = f[(size_t)c * N_PIX]; s = fmaf(x, x, s); }
    red[part][pl] = s;
    __syncthreads();
    if (t < 64) {
        float tot = red[0][t] + red[1][t] + red[2][t] + red[3][t];
        rnorm[pix0 + t] = 16.0f / fmaxf(sqrtf(tot), 1e-12f);
    }
}

// ---------------------------------------------------------------------------
// Kernel 2: projection GEMM -> fp16 Kst/Vst in XOR-slotted tile layout,
// cksq [bh][p] = 0.125*log2e*sum_d qh^2 (from ROUNDED fp16 q -> diag max exact).
//
// Kst[bh][tile][j][slot][8]: element (j, d) at j*64 + ((d>>3) ^ (j&7))*8 + (d&7)
// Vst[bh][tile][d][slot][8]: the 16B slot (d, sv=kv*4+g) holds, at half e,
//   V[d][ j = kv*32 + (e>>2)*16 + g*4 + (e&3) ], slot stored at sv ^ (d&7).
// Both give bank-balanced ds_read_b128 fragments from a LINEAR LDS copy.
// ---------------------------------------------------------------------------
__global__ __launch_bounds__(256) void proj_kernel(
    const float* __restrict__ fmap, const float* __restrict__ gamma,
    const float* __restrict__ Wq, const float* __restrict__ Wv,
    const float* __restrict__ rnorm,
    _Float16* __restrict__ Kst, _Float16* __restrict__ Vst,
    float* __restrict__ cksq) {
    const int pt = blockIdx.x, mt = blockIdx.y, b = blockIdx.z;
    const int p0 = pt * 64, m0 = mt * 64;
    const bool isQ = (m0 < DINNER);
    const float* W = isQ ? Wq : Wv;
    const int or0 = isQ ? m0 : m0 - DINNER;
    const int h = or0 >> 6;           // head
    const int bh = b * 8 + h;

    __shared__ float As[16][68];
    __shared__ float Bs[16][68];
    const int t = threadIdx.x, tm = t >> 4, tn = t & 15;
    float acc[4][4] = {};

    for (int kt = 0; kt < CDIM; kt += 16) {
        __syncthreads();
        for (int e = t; e < 1024; e += 256) {
            int m = e >> 4, kk = e & 15;
            As[kk][m] = W[(size_t)(or0 + m) * CDIM + kt + kk] * gamma[kt + kk];
        }
        for (int e = t; e < 1024; e += 256) {
            int kk = e >> 6, pp = e & 63;
            Bs[kk][pp] = fmap[((size_t)b * CDIM + kt + kk) * N_PIX + p0 + pp];
        }
        __syncthreads();
        #pragma unroll
        for (int kk = 0; kk < 16; ++kk) {
            vf4 a = *(const vf4*)&As[kk][4 * tm];
            vf4 bb = *(const vf4*)&Bs[kk][4 * tn];
            #pragma unroll
            for (int r = 0; r < 4; ++r)
                #pragma unroll
                for (int c = 0; c < 4; ++c)
                    acc[r][c] = fmaf(a[r], bb[c], acc[r][c]);
        }
    }

    // apply rnorm, round to fp16
    _Float16 hq[4][4];
    float part[4] = {0.f, 0.f, 0.f, 0.f};
    #pragma unroll
    for (int c = 0; c < 4; ++c) {
        float rn = rnorm[b * N_PIX + p0 + 4 * tn + c];
        #pragma unroll
        for (int r = 0; r < 4; ++r) {
            _Float16 hv = (_Float16)(acc[r][c] * rn);
            hq[r][c] = hv;
            float qrf = (float)hv;
            part[c] = fmaf(qrf, qrf, part[c]);
        }
    }

    if (isQ) {
        _Float16* kt2 = Kst + ((size_t)bh * 64 + pt) * 4096;
        #pragma unroll
        for (int c = 0; c < 4; ++c) {
            const int j = 4 * tn + c;
            half4v hv = {hq[0][c], hq[1][c], hq[2][c], hq[3][c]};
            // d = 4*tm .. 4*tm+3: slot = tm>>1, in-slot half offset 4*(tm&1)
            *(half4v*)(kt2 + j * 64 + (((tm >> 1) ^ (j & 7)) * 8) + (tm & 1) * 4) = hv;
        }
        // reduce per-pixel ksq over the 16 tm groups via LDS (reuse Bs)
        __syncthreads();
        *(vf4*)&Bs[tm][4 * tn] = vf4{part[0], part[1], part[2], part[3]};
        __syncthreads();
        if (t < 64) {
            float s = 0.f;
            #pragma unroll
            for (int r = 0; r < 16; ++r) s += Bs[r][t];
            cksq[(size_t)bh * N_PIX + p0 + t] = CKSQ_SCALE * s;
        }
    } else {
        _Float16* vt2 = Vst + ((size_t)bh * 64 + pt) * 4096;
        // j = 4*tn + c -> kv = tn>>3, hi = (tn>>2)&1, gg = tn&3
        const int kv = tn >> 3, gg = tn & 3, hi = (tn >> 2) & 1;
        const int sv = kv * 4 + gg;
        #pragma unroll
        for (int r = 0; r < 4; ++r) {
            const int d = 4 * tm + r;
            half4v hv = {hq[r][0], hq[r][1], hq[r][2], hq[r][3]};
            *(half4v*)(vt2 + d * 64 + ((sv ^ (d & 7)) * 8) + hi * 4) = hv;
        }
    }
}

// ---------------------------------------------------------------------------
// Kernel 3: fp16 MFMA flash attention via SWAPPED QK^T (S^T = mfma(K, Q)),
// with LDS double-buffered K/V tile staging (global_load_lds, zero VGPR cost).
// k = q; null kv analytic; m_i = max(0.125*qsq_i, nullsim_i) known upfront.
// Block = 4 waves x 32 q-rows, all waves share the staged tiles.
// ---------------------------------------------------------------------------
__global__ __launch_bounds__(256, 2) void attn_kernel(
    const _Float16* __restrict__ Kst,  // [bh][64][4096] xor-slotted
    const _Float16* __restrict__ Vst,  // [bh][64][4096] xor-slotted
    const float* __restrict__ cksq,    // [bh][p] = 0.125*log2e*ksq
    const float* __restrict__ nullkv,  // [2][8][64] fp32
    float* __restrict__ AO)            // [b][512][p]
{
    const int n = blockIdx.x;
    const int slot = n >> 3;
    const int bh = (n & 7) * 2 + (slot >> 5);   // XCD swizzle: 2 bh per XCD
    const int it = slot & 31;
    const int h = bh & 7;

    __shared__ __align__(16) _Float16 Klds[2][4096];
    __shared__ __align__(16) _Float16 Vlds[2][4096];
    __shared__ __align__(16) float ksq_lds[4096];

    const int t = threadIdx.x;
    const int w = t >> 6;
    const int lane = t & 63;
    const int col = lane & 15;
    const int g = lane >> 4;
    const int c7 = col & 7;

    // ksq to LDS (vectorized)
    const float* ck = cksq + (size_t)bh * N_PIX;
    #pragma unroll
    for (int e = 0; e < 4; ++e)
        *(vf4*)&ksq_lds[t * 4 + e * 1024] = *(const vf4*)&ck[t * 4 + e * 1024];

    const _Float16* kbase = Kst + (size_t)bh * (64 * 4096);
    const _Float16* vbase = Vst + (size_t)bh * (64 * 4096);
    const int i0 = it * 128 + w * 32;

    // prologue: stage tile 0 (wave w stages chunks 2w, 2w+1 of K and V)
    {
        const int ch = w * 2;
        #pragma unroll
        for (int q = 0; q < 2; ++q) {
            GLOAD_LDS16(kbase + (ch + q) * 512 + lane * 8, &Klds[0][(ch + q) * 512]);
            GLOAD_LDS16(vbase + (ch + q) * 512 + lane * 8, &Vlds[0][(ch + q) * 512]);
        }
    }

    // Q fragments (B-operand of S^T mfma) from global Kst: d = dk*32+g*8+e
    half8 qf[2][2];
    #pragma unroll
    for (int s = 0; s < 2; ++s) {
        const int i = i0 + s * 16 + col;
        #pragma unroll
        for (int dk = 0; dk < 2; ++dk)
            qf[s][dk] = *(const half8*)(kbase + (size_t)(i >> 6) * 4096 +
                                        (i & 63) * 64 + ((dk * 4 + g) ^ c7) * 8);
    }

    // null kv: per-lane nd for q-row = l&15 after g-group reduction
    float nkv[2][8];
    #pragma unroll
    for (int dk = 0; dk < 2; ++dk) {
        const float* np = nullkv + h * 64 + dk * 32 + g * 8;
        vf4 a = *(const vf4*)np;
        vf4 b2 = *(const vf4*)(np + 4);
        nkv[dk][0] = a[0]; nkv[dk][1] = a[1]; nkv[dk][2] = a[2]; nkv[dk][3] = a[3];
        nkv[dk][4] = b2[0]; nkv[dk][5] = b2[1]; nkv[dk][6] = b2[2]; nkv[dk][7] = b2[3];
    }
    float nd0 = 0.f, nd1 = 0.f, nkk = 0.f;
    #pragma unroll
    for (int dk = 0; dk < 2; ++dk)
        #pragma unroll
        for (int e = 0; e < 8; ++e) {
            float nkval = nkv[dk][e];
            nkk = fmaf(nkval, nkval, nkk);
            nd0 = fmaf((float)qf[0][dk][e], nkval, nd0);
            nd1 = fmaf((float)qf[1][dk][e], nkval, nd1);
        }
    nd0 += __shfl_xor(nd0, 16); nd0 += __shfl_xor(nd0, 32);
    nd1 += __shfl_xor(nd1, 16); nd1 += __shfl_xor(nd1, 32);
    nkk += __shfl_xor(nkk, 16); nkk += __shfl_xor(nkk, 32);

    // null V values at d = dt*16 + 4g + r (matches O^T D-layout)
    vf4 nv4[4];
    #pragma unroll
    for (int dt = 0; dt < 4; ++dt)
        nv4[dt] = *(const vf4*)(nullkv + DINNER + h * 64 + dt * 16 + 4 * g);

    __syncthreads();   // ksq + tile 0 staged

    float m_[2], l_[2];
    f32x4 oaccT[2][4];
    #pragma unroll
    for (int s = 0; s < 2; ++s) {
        float ndv = (s == 0) ? nd0 : nd1;
        float nsim = fmaf(0.25f, ndv, -0.125f * nkk) * LOG2E;
        float ci = ksq_lds[i0 + s * 16 + col];
        float m = fmaxf(ci, nsim);
        m_[s] = m;
        float wn = exp2f(nsim - m);
        l_[s] = wn * 0.25f;               // null l split across the 4 g-lanes
        #pragma unroll
        for (int dt = 0; dt < 4; ++dt)
            #pragma unroll
            for (int r = 0; r < 4; ++r)
                oaccT[s][dt][r] = wn * nv4[dt][r];
    }

    int cb = 0;
    #pragma unroll 1
    for (int jt64 = 0; jt64 < 64; ++jt64) {
        // stage next tile into the other buffer (async, drains at barrier)
        if (jt64 < 63) {
            const _Float16* kt = kbase + (size_t)(jt64 + 1) * 4096;
            const _Float16* vt = vbase + (size_t)(jt64 + 1) * 4096;
            const int ch = w * 2;
            #pragma unroll
            for (int q = 0; q < 2; ++q) {
                GLOAD_LDS16(kt + (ch + q) * 512 + lane * 8, &Klds[cb ^ 1][(ch + q) * 512]);
                GLOAD_LDS16(vt + (ch + q) * 512 + lane * 8, &Vlds[cb ^ 1][(ch + q) * 512]);
            }
        }
        const int j0 = jt64 * 64;
        const _Float16* kl = &Klds[cb][0];
        const _Float16* vl = &Vlds[cb][0];

        // ksq (log2-scaled) for this lane's j values: j = jt*16 + 4g + r
        vf4 cj[4];
        #pragma unroll
        for (int jt = 0; jt < 4; ++jt)
            cj[jt] = *(const vf4*)&ksq_lds[j0 + jt * 16 + 4 * g];

        #pragma unroll
        for (int s = 0; s < 2; ++s) {
            // K fragments from LDS: row j = jt*16+col, slot (dk*4+g)^c7
            half8 kf[4][2];
            #pragma unroll
            for (int jt = 0; jt < 4; ++jt)
                #pragma unroll
                for (int dk = 0; dk < 2; ++dk)
                    kf[jt][dk] = *(const half8*)(kl + (jt * 16 + col) * 64 +
                                                 ((dk * 4 + g) ^ c7) * 8);
            f32x4 sfT[4];
            __builtin_amdgcn_s_setprio(1);
            #pragma unroll
            for (int jt = 0; jt < 4; ++jt) {
                sfT[jt] = f32x4{0.f, 0.f, 0.f, 0.f};
                sfT[jt] = __builtin_amdgcn_mfma_f32_16x16x32_f16(kf[jt][0], qf[s][0], sfT[jt], 0, 0, 0);
                sfT[jt] = __builtin_amdgcn_mfma_f32_16x16x32_f16(kf[jt][1], qf[s][1], sfT[jt], 0, 0, 0);
            }
            __builtin_amdgcn_s_setprio(0);
            // softmax in exp2 domain: m fixed (diag max), i = l&15 per lane
            const float m = m_[s];
            float pv[4][4];
            float lp0 = 0.f, lp1 = 0.f;
            #pragma unroll
            for (int jt = 0; jt < 4; ++jt)
                #pragma unroll
                for (int r = 0; r < 4; ++r) {
                    float p = exp2f(fmaf(C1, sfT[jt][r], -cj[jt][r] - m));
                    pv[jt][r] = p;
                    if (jt < 2) lp0 += p; else lp1 += p;
                }
            l_[s] += lp0 + lp1;
            half8 pf0 = {(_Float16)pv[0][0], (_Float16)pv[0][1], (_Float16)pv[0][2], (_Float16)pv[0][3],
                         (_Float16)pv[1][0], (_Float16)pv[1][1], (_Float16)pv[1][2], (_Float16)pv[1][3]};
            half8 pf1 = {(_Float16)pv[2][0], (_Float16)pv[2][1], (_Float16)pv[2][2], (_Float16)pv[2][3],
                         (_Float16)pv[3][0], (_Float16)pv[3][1], (_Float16)pv[3][2], (_Float16)pv[3][3]};
            // O^T[d][i] += sum_j V[d][j] * P[i][j], V frags from LDS
            __builtin_amdgcn_s_setprio(1);
            #pragma unroll
            for (int dt = 0; dt < 4; ++dt) {
                half8 v0 = *(const half8*)(vl + (dt * 16 + col) * 64 + ((0 * 4 + g) ^ c7) * 8);
                half8 v1 = *(const half8*)(vl + (dt * 16 + col) * 64 + ((1 * 4 + g) ^ c7) * 8);
                oaccT[s][dt] = __builtin_amdgcn_mfma_f32_16x16x32_f16(v0, pf0, oaccT[s][dt], 0, 0, 0);
                oaccT[s][dt] = __builtin_amdgcn_mfma_f32_16x16x32_f16(v1, pf1, oaccT[s][dt], 0, 0, 0);
            }
            __builtin_amdgcn_s_setprio(0);
        }
        __syncthreads();   // staging of tile+1 complete; reads of tile done
        cb ^= 1;
    }

    // epilogue: reduce l over the 4 g-lanes, normalize, store
    float* aob = AO + ((size_t)(bh >> 3) * DINNER + h * 64) * N_PIX;
    #pragma unroll
    for (int s = 0; s < 2; ++s) {
        float l = l_[s];
        l += __shfl_xor(l, 16); l += __shfl_xor(l, 32);
        float linv = 1.f / l;
        const int p = i0 + s * 16 + col;
        #pragma unroll
        for (int dt = 0; dt < 4; ++dt)
            #pragma unroll
            for (int r = 0; r < 4; ++r)
                aob[(size_t)(dt * 16 + 4 * g + r) * N_PIX + p] = oaccT[s][dt][r] * linv;
    }
}

// ---------------------------------------------------------------------------
// Kernel 4: output GEMM  out[o=256][p] = sum_c Wout[o][c] * AO[b][c][p]
// ---------------------------------------------------------------------------
__global__ __launch_bounds__(256) void outproj_kernel(
    const float* __restrict__ AO, const float* __restrict__ Wout,
    float* __restrict__ out) {
    const int pt = blockIdx.x, mt = blockIdx.y, b = blockIdx.z;
    const int p0 = pt * 64, m0 = mt * 64;
    __shared__ float As[16][68];
    __shared__ float Bs[16][68];
    const int t = threadIdx.x, tm = t >> 4, tn = t & 15;
    float acc[4][4] = {};
    for (int kt = 0; kt < DINNER; kt += 16) {
        __syncthreads();
        for (int e = t; e < 1024; e += 256) {
            int m = e >> 4, kk = e & 15;
            As[kk][m] = Wout[(size_t)(m0 + m) * DINNER + kt + kk];
        }
        for (int e = t; e < 1024; e += 256) {
            int kk = e >> 6, pp = e & 63;
            Bs[kk][pp] = AO[((size_t)b * DINNER + kt + kk) * N_PIX + p0 + pp];
        }
        __syncthreads();
        #pragma unroll
        for (int kk = 0; kk < 16; ++kk) {
            vf4 a = *(const vf4*)&As[kk][4 * tm];
            vf4 bb = *(const vf4*)&Bs[kk][4 * tn];
            #pragma unroll
            for (int r = 0; r < 4; ++r)
                #pragma unroll
                for (int c = 0; c < 4; ++c)
                    acc[r][c] = fmaf(a[r], bb[c], acc[r][c]);
        }
    }
    #pragma unroll
    for (int r = 0; r < 4; ++r) {
        vf4 o4 = {acc[r][0], acc[r][1], acc[r][2], acc[r][3]};
        *(vf4*)&out[((size_t)b * CDIM + m0 + 4 * tm + r) * N_PIX + p0 + 4 * tn] = o4;
    }
}

// ---------------------------------------------------------------------------
extern "C" void kernel_launch(void* const* d_in, const int* in_sizes, int n_in,
                              void* d_out, int out_size, void* d_ws, size_t ws_size,
                              hipStream_t stream) {
    const float* fmap   = (const float*)d_in[0];
    const float* gamma  = (const float*)d_in[1];
    const float* Wq     = (const float*)d_in[2];
    const float* Wv     = (const float*)d_in[3];
    const float* Wout   = (const float*)d_in[4];
    const float* nullkv = (const float*)d_in[5];
    float* out = (float*)d_out;

    char* wsb = (char*)d_ws;
    _Float16* Kst = (_Float16*)wsb;                          // 8 MB
    _Float16* Vst = (_Float16*)(wsb + (8u << 20));           // 8 MB
    float*    AO  = (float*)(wsb + (16u << 20));             // 16 MB
    float*    cksq = (float*)(wsb + (32u << 20));            // 256 KB
    float*    rnorm = (float*)(wsb + (33u << 20));           // 32 KB

    rnorm_kernel<<<128, 256, 0, stream>>>(fmap, rnorm);
    proj_kernel<<<dim3(64, 16, 2), 256, 0, stream>>>(fmap, gamma, Wq, Wv, rnorm, Kst, Vst, cksq);
    attn_kernel<<<512, 256, 0, stream>>>(Kst, Vst, cksq, nullkv, AO);
    outproj_kernel<<<dim3(64, 4, 2), 256, 0, stream>>>(AO, Wout, out);
}

// Round 7
// 282.805 us; speedup vs baseline: 2.8942x; 1.0202x over previous
//
#include <hip/hip_runtime.h>
#include <math.h>
#include <stdint.h>

#define N_PIX 4096
#define CDIM 256
#define DINNER 512

typedef float vf4 __attribute__((ext_vector_type(4)));
typedef float f32x4 __attribute__((ext_vector_type(4)));
typedef _Float16 half8 __attribute__((ext_vector_type(8)));
typedef _Float16 half4v __attribute__((ext_vector_type(4)));

// log2(e) scalings: softmax done in exp2 domain
#define LOG2E 1.44269504f
#define CKSQ_SCALE 0.18033688f   /* 0.125 * log2e */
#define C1 0.36067376f           /* 0.25  * log2e */

// async global->LDS, 16B per lane, LDS dest = wave-uniform base + lane*16
#define GLOAD_LDS16(g, l)                                                  \
    __builtin_amdgcn_global_load_lds(                                      \
        (const __attribute__((address_space(1))) unsigned int*)(g),       \
        (__attribute__((address_space(3))) unsigned int*)(l), 16, 0, 0)

// ---------------------------------------------------------------------------
// Kernel 1: per-pixel channel L2 norm -> rnorm = sqrt(256)/max(||x||,1e-12)
// ---------------------------------------------------------------------------
__global__ __launch_bounds__(256) void rnorm_kernel(const float* __restrict__ fmap,
                                                    float* __restrict__ rnorm) {
    __shared__ float red[4][64];
    const int t = threadIdx.x;
    const int pl = t & 63;
    const int part = t >> 6;
    const int pix0 = blockIdx.x * 64;
    const int gp = pix0 + pl;
    const int b = gp >> 12, p = gp & 4095;
    const float* f = fmap + ((size_t)b * CDIM + part * 64) * N_PIX + p;
    float s = 0.f;
    #pragma unroll 8
    for (int c = 0; c < 64; ++c) { float x = f[(size_t)c * N_PIX]; s = fmaf(x, x, s); }
    red[part][pl] = s;
    __syncthreads();
    if (t < 64) {
        float tot = red[0][t] + red[1][t] + red[2][t] + red[3][t];
        rnorm[pix0 + t] = 16.0f / fmaxf(sqrtf(tot), 1e-12f);
    }
}

// ---------------------------------------------------------------------------
// Kernel 2: projection GEMM -> fp16 Kst/Vst in XOR-slotted tile layout,
// cksq [bh][p] = 0.125*log2e*sum_d qh^2 (from ROUNDED fp16 q -> diag max exact).
//
// Kst[bh][tile][j][slot][8]: element (j, d) at j*64 + ((d>>3) ^ (j&7))*8 + (d&7)
// Vst[bh][tile][d][slot][8]: the 16B slot (d, sv=kv*4+g) holds, at half e,
//   V[d][ j = kv*32 + (e>>2)*16 + g*4 + (e&3) ], slot stored at sv ^ (d&7).
// Both give bank-balanced ds_read_b128 fragments from a LINEAR LDS copy.
// ---------------------------------------------------------------------------
__global__ __launch_bounds__(256) void proj_kernel(
    const float* __restrict__ fmap, const float* __restrict__ gamma,
    const float* __restrict__ Wq, const float* __restrict__ Wv,
    const float* __restrict__ rnorm,
    _Float16* __restrict__ Kst, _Float16* __restrict__ Vst,
    float* __restrict__ cksq) {
    const int pt = blockIdx.x, mt = blockIdx.y, b = blockIdx.z;
    const int p0 = pt * 64, m0 = mt * 64;
    const bool isQ = (m0 < DINNER);
    const float* W = isQ ? Wq : Wv;
    const int or0 = isQ ? m0 : m0 - DINNER;
    const int h = or0 >> 6;           // head
    const int bh = b * 8 + h;

    __shared__ float As[16][68];
    __shared__ float Bs[16][68];
    const int t = threadIdx.x, tm = t >> 4, tn = t & 15;
    float acc[4][4] = {};

    for (int kt = 0; kt < CDIM; kt += 16) {
        __syncthreads();
        for (int e = t; e < 1024; e += 256) {
            int m = e >> 4, kk = e & 15;
            As[kk][m] = W[(size_t)(or0 + m) * CDIM + kt + kk] * gamma[kt + kk];
        }
        for (int e = t; e < 1024; e += 256) {
            int kk = e >> 6, pp = e & 63;
            Bs[kk][pp] = fmap[((size_t)b * CDIM + kt + kk) * N_PIX + p0 + pp];
        }
        __syncthreads();
        #pragma unroll
        for (int kk = 0; kk < 16; ++kk) {
            vf4 a = *(const vf4*)&As[kk][4 * tm];
            vf4 bb = *(const vf4*)&Bs[kk][4 * tn];
            #pragma unroll
            for (int r = 0; r < 4; ++r)
                #pragma unroll
                for (int c = 0; c < 4; ++c)
                    acc[r][c] = fmaf(a[r], bb[c], acc[r][c]);
        }
    }

    // apply rnorm, round to fp16
    _Float16 hq[4][4];
    float part[4] = {0.f, 0.f, 0.f, 0.f};
    #pragma unroll
    for (int c = 0; c < 4; ++c) {
        float rn = rnorm[b * N_PIX + p0 + 4 * tn + c];
        #pragma unroll
        for (int r = 0; r < 4; ++r) {
            _Float16 hv = (_Float16)(acc[r][c] * rn);
            hq[r][c] = hv;
            float qrf = (float)hv;
            part[c] = fmaf(qrf, qrf, part[c]);
        }
    }

    if (isQ) {
        _Float16* kt2 = Kst + ((size_t)bh * 64 + pt) * 4096;
        #pragma unroll
        for (int c = 0; c < 4; ++c) {
            const int j = 4 * tn + c;
            half4v hv = {hq[0][c], hq[1][c], hq[2][c], hq[3][c]};
            // d = 4*tm .. 4*tm+3: slot = tm>>1, in-slot half offset 4*(tm&1)
            *(half4v*)(kt2 + j * 64 + (((tm >> 1) ^ (j & 7)) * 8) + (tm & 1) * 4) = hv;
        }
        // reduce per-pixel ksq over the 16 tm groups via LDS (reuse Bs)
        __syncthreads();
        *(vf4*)&Bs[tm][4 * tn] = vf4{part[0], part[1], part[2], part[3]};
        __syncthreads();
        if (t < 64) {
            float s = 0.f;
            #pragma unroll
            for (int r = 0; r < 16; ++r) s += Bs[r][t];
            cksq[(size_t)bh * N_PIX + p0 + t] = CKSQ_SCALE * s;
        }
    } else {
        _Float16* vt2 = Vst + ((size_t)bh * 64 + pt) * 4096;
        // j = 4*tn + c -> kv = tn>>3, hi = (tn>>2)&1, gg = tn&3
        const int kv = tn >> 3, gg = tn & 3, hi = (tn >> 2) & 1;
        const int sv = kv * 4 + gg;
        #pragma unroll
        for (int r = 0; r < 4; ++r) {
            const int d = 4 * tm + r;
            half4v hv = {hq[r][0], hq[r][1], hq[r][2], hq[r][3]};
            *(half4v*)(vt2 + d * 64 + ((sv ^ (d & 7)) * 8) + hi * 4) = hv;
        }
    }
}

// ---------------------------------------------------------------------------
// Kernel 3: fp16 MFMA flash attention via SWAPPED QK^T (S^T = mfma(K, Q)),
// LDS double-buffered K/V staging (global_load_lds), 8 waves x 16 q-rows.
// k = q; null kv analytic; m_i = max(0.125*qsq_i, nullsim_i) known upfront.
// All 8 waves share the staged tiles; cj/ksq read direct from L2 (16 KB/bh).
// ---------------------------------------------------------------------------
__global__ __launch_bounds__(512, 4) void attn_kernel(
    const _Float16* __restrict__ Kst,  // [bh][64][4096] xor-slotted
    const _Float16* __restrict__ Vst,  // [bh][64][4096] xor-slotted
    const float* __restrict__ cksq,    // [bh][p] = 0.125*log2e*ksq
    const float* __restrict__ nullkv,  // [2][8][64] fp32
    float* __restrict__ AO)            // [b][512][p]
{
    const int n = blockIdx.x;
    const int slot = n >> 3;
    const int bh = (n & 7) * 2 + (slot >> 5);   // XCD swizzle: 2 bh per XCD
    const int it = slot & 31;
    const int h = bh & 7;

    __shared__ __align__(16) _Float16 Klds[2][4096];
    __shared__ __align__(16) _Float16 Vlds[2][4096];

    const int t = threadIdx.x;
    const int w = t >> 6;          // 0..7
    const int lane = t & 63;
    const int col = lane & 15;
    const int g = lane >> 4;
    const int c7 = col & 7;

    const _Float16* kbase = Kst + (size_t)bh * (64 * 4096);
    const _Float16* vbase = Vst + (size_t)bh * (64 * 4096);
    const float* ck = cksq + (size_t)bh * N_PIX;
    const int i0 = it * 128 + w * 16;

    // prologue: stage tile 0 (wave w stages chunk w of K and V)
    GLOAD_LDS16(kbase + w * 512 + lane * 8, &Klds[0][w * 512]);
    GLOAD_LDS16(vbase + w * 512 + lane * 8, &Vlds[0][w * 512]);

    // Q fragment (B-operand of S^T mfma) from global Kst: d = dk*32+g*8+e
    half8 qf[2];
    {
        const int i = i0 + col;
        #pragma unroll
        for (int dk = 0; dk < 2; ++dk)
            qf[dk] = *(const half8*)(kbase + (size_t)(i >> 6) * 4096 +
                                     (i & 63) * 64 + ((dk * 4 + g) ^ c7) * 8);
    }

    // null kv: per-lane nd for q-row = l&15 after g-group reduction
    float nd = 0.f, nkk = 0.f;
    #pragma unroll
    for (int dk = 0; dk < 2; ++dk) {
        const float* np = nullkv + h * 64 + dk * 32 + g * 8;
        #pragma unroll
        for (int e = 0; e < 8; ++e) {
            float nkval = np[e];
            nkk = fmaf(nkval, nkval, nkk);
            nd = fmaf((float)qf[dk][e], nkval, nd);
        }
    }
    nd += __shfl_xor(nd, 16); nd += __shfl_xor(nd, 32);
    nkk += __shfl_xor(nkk, 16); nkk += __shfl_xor(nkk, 32);

    // null V values at d = dt*16 + 4g + r (matches O^T D-layout)
    vf4 nv4[4];
    #pragma unroll
    for (int dt = 0; dt < 4; ++dt)
        nv4[dt] = *(const vf4*)(nullkv + DINNER + h * 64 + dt * 16 + 4 * g);

    float m_, l_;
    f32x4 oaccT[4];
    {
        float nsim = fmaf(0.25f, nd, -0.125f * nkk) * LOG2E;
        float ci = ck[i0 + col];
        m_ = fmaxf(ci, nsim);
        float wn = exp2f(nsim - m_);
        l_ = wn * 0.25f;                  // null l split across the 4 g-lanes
        #pragma unroll
        for (int dt = 0; dt < 4; ++dt)
            #pragma unroll
            for (int r = 0; r < 4; ++r)
                oaccT[dt][r] = wn * nv4[dt][r];
    }

    __syncthreads();   // tile 0 staged

    int cb = 0;
    #pragma unroll 1
    for (int jt64 = 0; jt64 < 64; ++jt64) {
        // stage next tile into the other buffer (async, drains at barrier)
        if (jt64 < 63) {
            const _Float16* kt = kbase + (size_t)(jt64 + 1) * 4096;
            const _Float16* vt = vbase + (size_t)(jt64 + 1) * 4096;
            GLOAD_LDS16(kt + w * 512 + lane * 8, &Klds[cb ^ 1][w * 512]);
            GLOAD_LDS16(vt + w * 512 + lane * 8, &Vlds[cb ^ 1][w * 512]);
        }
        const int j0 = jt64 * 64;
        const _Float16* kl = &Klds[cb][0];
        const _Float16* vl = &Vlds[cb][0];

        // ksq (log2-scaled) from L2: j = jt*16 + 4g + r
        vf4 cj[4];
        #pragma unroll
        for (int jt = 0; jt < 4; ++jt)
            cj[jt] = *(const vf4*)&ck[j0 + jt * 16 + 4 * g];

        // K fragments from LDS: row j = jt*16+col, slot (dk*4+g)^c7
        half8 kf[4][2];
        #pragma unroll
        for (int jt = 0; jt < 4; ++jt)
            #pragma unroll
            for (int dk = 0; dk < 2; ++dk)
                kf[jt][dk] = *(const half8*)(kl + (jt * 16 + col) * 64 +
                                             ((dk * 4 + g) ^ c7) * 8);
        f32x4 sfT[4];
        __builtin_amdgcn_s_setprio(1);
        #pragma unroll
        for (int jt = 0; jt < 4; ++jt) {
            sfT[jt] = f32x4{0.f, 0.f, 0.f, 0.f};
            sfT[jt] = __builtin_amdgcn_mfma_f32_16x16x32_f16(kf[jt][0], qf[0], sfT[jt], 0, 0, 0);
            sfT[jt] = __builtin_amdgcn_mfma_f32_16x16x32_f16(kf[jt][1], qf[1], sfT[jt], 0, 0, 0);
        }
        __builtin_amdgcn_s_setprio(0);
        // softmax in exp2 domain: m fixed (diag max), i = l&15 per lane
        float pv[4][4];
        float lp0 = 0.f, lp1 = 0.f;
        #pragma unroll
        for (int jt = 0; jt < 4; ++jt)
            #pragma unroll
            for (int r = 0; r < 4; ++r) {
                float p = exp2f(fmaf(C1, sfT[jt][r], -cj[jt][r] - m_));
                pv[jt][r] = p;
                if (jt < 2) lp0 += p; else lp1 += p;
            }
        l_ += lp0 + lp1;
        half8 pf0 = {(_Float16)pv[0][0], (_Float16)pv[0][1], (_Float16)pv[0][2], (_Float16)pv[0][3],
                     (_Float16)pv[1][0], (_Float16)pv[1][1], (_Float16)pv[1][2], (_Float16)pv[1][3]};
        half8 pf1 = {(_Float16)pv[2][0], (_Float16)pv[2][1], (_Float16)pv[2][2], (_Float16)pv[2][3],
                     (_Float16)pv[3][0], (_Float16)pv[3][1], (_Float16)pv[3][2], (_Float16)pv[3][3]};
        // O^T[d][i] += sum_j V[d][j] * P[i][j], V frags from LDS
        __builtin_amdgcn_s_setprio(1);
        #pragma unroll
        for (int dt = 0; dt < 4; ++dt) {
            half8 v0 = *(const half8*)(vl + (dt * 16 + col) * 64 + ((0 * 4 + g) ^ c7) * 8);
            half8 v1 = *(const half8*)(vl + (dt * 16 + col) * 64 + ((1 * 4 + g) ^ c7) * 8);
            oaccT[dt] = __builtin_amdgcn_mfma_f32_16x16x32_f16(v0, pf0, oaccT[dt], 0, 0, 0);
            oaccT[dt] = __builtin_amdgcn_mfma_f32_16x16x32_f16(v1, pf1, oaccT[dt], 0, 0, 0);
        }
        __builtin_amdgcn_s_setprio(0);
        __syncthreads();   // staging of tile+1 complete; reads of tile done
        cb ^= 1;
    }

    // epilogue: reduce l over the 4 g-lanes, normalize, store
    float* aob = AO + ((size_t)(bh >> 3) * DINNER + h * 64) * N_PIX;
    {
        float l = l_;
        l += __shfl_xor(l, 16); l += __shfl_xor(l, 32);
        float linv = 1.f / l;
        const int p = i0 + col;
        #pragma unroll
        for (int dt = 0; dt < 4; ++dt)
            #pragma unroll
            for (int r = 0; r < 4; ++r)
                aob[(size_t)(dt * 16 + 4 * g + r) * N_PIX + p] = oaccT[dt][r] * linv;
    }
}

// ---------------------------------------------------------------------------
// Kernel 4: output GEMM  out[o=256][p] = sum_c Wout[o][c] * AO[b][c][p]
// ---------------------------------------------------------------------------
__global__ __launch_bounds__(256) void outproj_kernel(
    const float* __restrict__ AO, const float* __restrict__ Wout,
    float* __restrict__ out) {
    const int pt = blockIdx.x, mt = blockIdx.y, b = blockIdx.z;
    const int p0 = pt * 64, m0 = mt * 64;
    __shared__ float As[16][68];
    __shared__ float Bs[16][68];
    const int t = threadIdx.x, tm = t >> 4, tn = t & 15;
    float acc[4][4] = {};
    for (int kt = 0; kt < DINNER; kt += 16) {
        __syncthreads();
        for (int e = t; e < 1024; e += 256) {
            int m = e >> 4, kk = e & 15;
            As[kk][m] = Wout[(size_t)(m0 + m) * DINNER + kt + kk];
        }
        for (int e = t; e < 1024; e += 256) {
            int kk = e >> 6, pp = e & 63;
            Bs[kk][pp] = AO[((size_t)b * DINNER + kt + kk) * N_PIX + p0 + pp];
        }
        __syncthreads();
        #pragma unroll
        for (int kk = 0; kk < 16; ++kk) {
            vf4 a = *(const vf4*)&As[kk][4 * tm];
            vf4 bb = *(const vf4*)&Bs[kk][4 * tn];
            #pragma unroll
            for (int r = 0; r < 4; ++r)
                #pragma unroll
                for (int c = 0; c < 4; ++c)
                    acc[r][c] = fmaf(a[r], bb[c], acc[r][c]);
        }
    }
    #pragma unroll
    for (int r = 0; r < 4; ++r) {
        vf4 o4 = {acc[r][0], acc[r][1], acc[r][2], acc[r][3]};
        *(vf4*)&out[((size_t)b * CDIM + m0 + 4 * tm + r) * N_PIX + p0 + 4 * tn] = o4;
    }
}

// ---------------------------------------------------------------------------
extern "C" void kernel_launch(void* const* d_in, const int* in_sizes, int n_in,
                              void* d_out, int out_size, void* d_ws, size_t ws_size,
                              hipStream_t stream) {
    const float* fmap   = (const float*)d_in[0];
    const float* gamma  = (const float*)d_in[1];
    const float* Wq     = (const float*)d_in[2];
    const float* Wv     = (const float*)d_in[3];
    const float* Wout   = (const float*)d_in[4];
    const float* nullkv = (const float*)d_in[5];
    float* out = (float*)d_out;

    char* wsb = (char*)d_ws;
    _Float16* Kst = (_Float16*)wsb;                          // 8 MB
    _Float16* Vst = (_Float16*)(wsb + (8u << 20));           // 8 MB
    float*    AO  = (float*)(wsb + (16u << 20));             // 16 MB
    float*    cksq = (float*)(wsb + (32u << 20));            // 256 KB
    float*    rnorm = (float*)(wsb + (33u << 20));           // 32 KB

    rnorm_kernel<<<128, 256, 0, stream>>>(fmap, rnorm);
    proj_kernel<<<dim3(64, 16, 2), 256, 0, stream>>>(fmap, gamma, Wq, Wv, rnorm, Kst, Vst, cksq);
    attn_kernel<<<512, 512, 0, stream>>>(Kst, Vst, cksq, nullkv, AO);
    outproj_kernel<<<dim3(64, 4, 2), 256, 0, stream>>>(AO, Wout, out);
}

// Round 9
// 247.314 us; speedup vs baseline: 3.3096x; 1.1435x over previous
//
#include <hip/hip_runtime.h>
#include <math.h>
#include <stdint.h>

#define N_PIX 4096
#define CDIM 256
#define DINNER 512

typedef float vf4 __attribute__((ext_vector_type(4)));
typedef float f32x4 __attribute__((ext_vector_type(4)));
typedef _Float16 half8 __attribute__((ext_vector_type(8)));
typedef _Float16 half4v __attribute__((ext_vector_type(4)));
typedef __fp16 fp16x2 __attribute__((ext_vector_type(2)));

// log2(e) scalings: softmax done in exp2 domain
#define LOG2E 1.44269504f
#define CKSQ_SCALE 0.18033688f   /* 0.125 * log2e */
#define C1 0.36067376f           /* 0.25  * log2e */

// async global->LDS, 16B per lane, LDS dest = wave-uniform base + lane*16
#define GLOAD_LDS16(g, l)                                                  \
    __builtin_amdgcn_global_load_lds(                                      \
        (const __attribute__((address_space(1))) unsigned int*)(g),       \
        (__attribute__((address_space(3))) unsigned int*)(l), 16, 0, 0)

// ---------------------------------------------------------------------------
// Kernel 1: per-pixel channel L2 norm -> rnorm = sqrt(256)/max(||x||,1e-12),
// fused with fp16 transpose of fmap: fmapT16[b*4096+p][c] = fp16(fmap[b][c][p]).
// Norm is computed from the fp32 values (pre-rounding).
// ---------------------------------------------------------------------------
__global__ __launch_bounds__(256) void rnorm_kernel(const float* __restrict__ fmap,
                                                    float* __restrict__ rnorm,
                                                    _Float16* __restrict__ fmapT16) {
    __shared__ float red[4][64];
    const int t = threadIdx.x;
    const int pl = t & 63;
    const int part = t >> 6;
    const int pix0 = blockIdx.x * 64;
    const int gp = pix0 + pl;
    const int b = gp >> 12, p = gp & 4095;
    const float* f = fmap + ((size_t)b * CDIM + part * 64) * N_PIX + p;
    _Float16* o16 = fmapT16 + (size_t)gp * CDIM + part * 64;
    float s = 0.f;
    #pragma unroll
    for (int c8 = 0; c8 < 64; c8 += 8) {
        half8 hv;
        #pragma unroll
        for (int e = 0; e < 8; ++e) {
            float x = f[(size_t)(c8 + e) * N_PIX];
            s = fmaf(x, x, s);
            hv[e] = (_Float16)x;
        }
        *(half8*)(o16 + c8) = hv;
    }
    red[part][pl] = s;
    __syncthreads();
    if (t < 64) {
        float tot = red[0][t] + red[1][t] + red[2][t] + red[3][t];
        rnorm[pix0 + t] = 16.0f / fmaxf(sqrtf(tot), 1e-12f);
    }
}

// ---------------------------------------------------------------------------
// Kernel 1b: Wg16[o][c] = fp16( (o<512 ? Wq[o] : Wv[o-512])[c] * gamma[c] )
// ---------------------------------------------------------------------------
__global__ __launch_bounds__(256) void wg16_kernel(
    const float* __restrict__ Wq, const float* __restrict__ Wv,
    const float* __restrict__ gamma, _Float16* __restrict__ Wg16) {
    const int t = threadIdx.x;
    const int o = blockIdx.x * 4 + (t >> 6);
    const int c = (t & 63) * 4;
    const float* W = (o < DINNER) ? (Wq + (size_t)o * CDIM)
                                  : (Wv + (size_t)(o - DINNER) * CDIM);
    vf4 wv = *(const vf4*)(W + c);
    vf4 gv = *(const vf4*)(gamma + c);
    half4v h = {(_Float16)(wv[0] * gv[0]), (_Float16)(wv[1] * gv[1]),
                (_Float16)(wv[2] * gv[2]), (_Float16)(wv[3] * gv[3])};
    *(half4v*)(Wg16 + (size_t)o * CDIM + c) = h;
}

// ---------------------------------------------------------------------------
// Kernel 2: fp16 MFMA projection GEMM.
// Block = 4 waves; tile = 64 m-rows (one head) x 64 pixels; wave w owns the
// 16 pixels [p0+w*16, p0+w*16+16).  K=256 in 8 steps of 32, fragments loaded
// straight from L2 (fmapT16 / Wg16 row-contiguous, k-map k = ks*32+g*8+e for
// BOTH operands).  Epilogue writes Kst/Vst in the xor-slotted attn layout and
// cksq from the ROUNDED fp16 q (diag max stays exact).
// ---------------------------------------------------------------------------
__global__ __launch_bounds__(256) void proj_mfma(
    const _Float16* __restrict__ fmapT16,  // [b*4096+p][256]
    const _Float16* __restrict__ Wg16,     // [1024][256]
    const float* __restrict__ rnorm,       // [8192]
    _Float16* __restrict__ Kst, _Float16* __restrict__ Vst,
    float* __restrict__ cksq) {
    const int pt = blockIdx.x;             // 64
    const int mt = blockIdx.y;             // 16 (0..7 Q, 8..15 V)
    const int b = blockIdx.z;              // 2
    const int m0 = mt * 64;
    const bool isQ = (m0 < DINNER);
    const int h = (m0 & 511) >> 6;
    const int bh = b * 8 + h;
    const int p0 = pt * 64;

    const int t = threadIdx.x;
    const int w = t >> 6;
    const int lane = t & 63;
    const int col = lane & 15;
    const int g = lane >> 4;
    const int p = p0 + w * 16 + col;       // this lane's pixel
    const int j = w * 16 + col;            // pixel within the 64-tile

    const _Float16* bbase = fmapT16 + ((size_t)b * N_PIX + p) * CDIM;
    const _Float16* abase = Wg16 + (size_t)m0 * CDIM;

    f32x4 acc[4] = {};
    #pragma unroll
    for (int ks = 0; ks < 8; ++ks) {
        half8 bf = *(const half8*)(bbase + ks * 32 + g * 8);
        #pragma unroll
        for (int ms = 0; ms < 4; ++ms) {
            half8 af = *(const half8*)(abase + (size_t)(ms * 16 + col) * CDIM + ks * 32 + g * 8);
            acc[ms] = __builtin_amdgcn_mfma_f32_16x16x32_f16(af, bf, acc[ms], 0, 0, 0);
        }
    }

    const float rn = rnorm[b * N_PIX + p];
    _Float16 qh[4][4];
    #pragma unroll
    for (int ms = 0; ms < 4; ++ms)
        #pragma unroll
        for (int r = 0; r < 4; ++r)
            qh[ms][r] = (_Float16)(acc[ms][r] * rn);

    if (isQ) {
        float qs = 0.f;
        #pragma unroll
        for (int ms = 0; ms < 4; ++ms)
            #pragma unroll
            for (int r = 0; r < 4; ++r) {
                float qv = (float)qh[ms][r];
                qs = fmaf(qv, qv, qs);
            }
        qs += __shfl_xor(qs, 16);
        qs += __shfl_xor(qs, 32);
        _Float16* kt2 = Kst + ((size_t)bh * 64 + pt) * 4096;
        #pragma unroll
        for (int ms = 0; ms < 4; ++ms) {
            half4v hv = {qh[ms][0], qh[ms][1], qh[ms][2], qh[ms][3]};
            *(half4v*)(kt2 + j * 64 + (((ms * 2 + (g >> 1)) ^ (j & 7)) * 8) + (g & 1) * 4) = hv;
        }
        if (g == 0)
            cksq[(size_t)bh * N_PIX + p] = CKSQ_SCALE * qs;
    } else {
        _Float16* vt2 = Vst + ((size_t)bh * 64 + pt) * 4096;
        const int svb = ((j >> 5) << 2) + ((j >> 2) & 3);
        const int off = ((j >> 4) & 1) * 4 + (j & 3);
        #pragma unroll
        for (int ms = 0; ms < 4; ++ms)
            #pragma unroll
            for (int r = 0; r < 4; ++r) {
                const int d = ms * 16 + 4 * g + r;
                vt2[d * 64 + ((svb ^ (d & 7)) << 3) + off] = qh[ms][r];
            }
    }
}

// ---------------------------------------------------------------------------
// Kernel 3: fp16 MFMA flash attention via SWAPPED QK^T (S^T = mfma(K, Q)),
// LDS double-buffered K/V staging (global_load_lds), 8 waves x 16 q-rows.
// l accumulated by ones-A MFMA (matrix pipe) instead of VALU adds; P packed
// with v_cvt_pkrtz.  m_i = max(0.125*qsq_i, nullsim_i) known upfront.
// ---------------------------------------------------------------------------
__global__ __launch_bounds__(512, 4) void attn_kernel(
    const _Float16* __restrict__ Kst,  // [bh][64][4096] xor-slotted
    const _Float16* __restrict__ Vst,  // [bh][64][4096] xor-slotted
    const float* __restrict__ cksq,    // [bh][p] = 0.125*log2e*ksq
    const float* __restrict__ nullkv,  // [2][8][64] fp32
    float* __restrict__ AO)            // [b][512][p]
{
    const int n = blockIdx.x;
    const int slot = n >> 3;
    const int bh = (n & 7) * 2 + (slot >> 5);   // XCD swizzle: 2 bh per XCD
    const int it = slot & 31;
    const int h = bh & 7;

    __shared__ __align__(16) _Float16 Klds[2][4096];
    __shared__ __align__(16) _Float16 Vlds[2][4096];

    const int t = threadIdx.x;
    const int w = t >> 6;          // 0..7
    const int lane = t & 63;
    const int col = lane & 15;
    const int g = lane >> 4;
    const int c7 = col & 7;

    const _Float16* kbase = Kst + (size_t)bh * (64 * 4096);
    const _Float16* vbase = Vst + (size_t)bh * (64 * 4096);
    const float* ck = cksq + (size_t)bh * N_PIX;
    const int i0 = it * 128 + w * 16;

    // prologue: stage tile 0 (wave w stages chunk w of K and V)
    GLOAD_LDS16(kbase + w * 512 + lane * 8, &Klds[0][w * 512]);
    GLOAD_LDS16(vbase + w * 512 + lane * 8, &Vlds[0][w * 512]);

    // Q fragment (B-operand of S^T mfma) from global Kst: d = dk*32+g*8+e
    half8 qf[2];
    {
        const int i = i0 + col;
        #pragma unroll
        for (int dk = 0; dk < 2; ++dk)
            qf[dk] = *(const half8*)(kbase + (size_t)(i >> 6) * 4096 +
                                     (i & 63) * 64 + ((dk * 4 + g) ^ c7) * 8);
    }

    // null kv: per-lane nd for q-row = l&15 after g-group reduction
    float nd = 0.f, nkk = 0.f;
    #pragma unroll
    for (int dk = 0; dk < 2; ++dk) {
        const float* np = nullkv + h * 64 + dk * 32 + g * 8;
        #pragma unroll
        for (int e = 0; e < 8; ++e) {
            float nkval = np[e];
            nkk = fmaf(nkval, nkval, nkk);
            nd = fmaf((float)qf[dk][e], nkval, nd);
        }
    }
    nd += __shfl_xor(nd, 16); nd += __shfl_xor(nd, 32);
    nkk += __shfl_xor(nkk, 16); nkk += __shfl_xor(nkk, 32);

    // null V values at d = dt*16 + 4g + r (matches O^T D-layout)
    vf4 nv4[4];
    #pragma unroll
    for (int dt = 0; dt < 4; ++dt)
        nv4[dt] = *(const vf4*)(nullkv + DINNER + h * 64 + dt * 16 + 4 * g);

    float m_;
    f32x4 oaccT[4];
    f32x4 lacc;
    {
        float nsim = fmaf(0.25f, nd, -0.125f * nkk) * LOG2E;
        float ci = ck[i0 + col];
        m_ = fmaxf(ci, nsim);
        float wn = exp2f(nsim - m_);
        lacc = f32x4{wn, wn, wn, wn};      // full null weight (no g-split now)
        #pragma unroll
        for (int dt = 0; dt < 4; ++dt)
            #pragma unroll
            for (int r = 0; r < 4; ++r)
                oaccT[dt][r] = wn * nv4[dt][r];
    }

    const half8 ones1 = {(_Float16)1.f, (_Float16)1.f, (_Float16)1.f, (_Float16)1.f,
                         (_Float16)1.f, (_Float16)1.f, (_Float16)1.f, (_Float16)1.f};

    __syncthreads();   // tile 0 staged

    int cb = 0;
    #pragma unroll 1
    for (int jt64 = 0; jt64 < 64; ++jt64) {
        // stage next tile into the other buffer (async, drains at barrier)
        if (jt64 < 63) {
            const _Float16* kt = kbase + (size_t)(jt64 + 1) * 4096;
            const _Float16* vt = vbase + (size_t)(jt64 + 1) * 4096;
            GLOAD_LDS16(kt + w * 512 + lane * 8, &Klds[cb ^ 1][w * 512]);
            GLOAD_LDS16(vt + w * 512 + lane * 8, &Vlds[cb ^ 1][w * 512]);
        }
        const int j0 = jt64 * 64;
        const _Float16* kl = &Klds[cb][0];
        const _Float16* vl = &Vlds[cb][0];

        // ksq (log2-scaled) from L2: j = jt*16 + 4g + r
        vf4 cj[4];
        #pragma unroll
        for (int jt = 0; jt < 4; ++jt)
            cj[jt] = *(const vf4*)&ck[j0 + jt * 16 + 4 * g];

        // K fragments from LDS: row j = jt*16+col, slot (dk*4+g)^c7
        half8 kf[4][2];
        #pragma unroll
        for (int jt = 0; jt < 4; ++jt)
            #pragma unroll
            for (int dk = 0; dk < 2; ++dk)
                kf[jt][dk] = *(const half8*)(kl + (jt * 16 + col) * 64 +
                                             ((dk * 4 + g) ^ c7) * 8);
        f32x4 sfT[4];
        __builtin_amdgcn_s_setprio(1);
        #pragma unroll
        for (int jt = 0; jt < 4; ++jt) {
            sfT[jt] = f32x4{0.f, 0.f, 0.f, 0.f};
            sfT[jt] = __builtin_amdgcn_mfma_f32_16x16x32_f16(kf[jt][0], qf[0], sfT[jt], 0, 0, 0);
            sfT[jt] = __builtin_amdgcn_mfma_f32_16x16x32_f16(kf[jt][1], qf[1], sfT[jt], 0, 0, 0);
        }
        __builtin_amdgcn_s_setprio(0);

        // softmax in exp2 domain: m fixed (diag max), i = l&15 per lane
        half8 pf0, pf1;
        {
            const float nm = -m_;
            #pragma unroll
            for (int jt = 0; jt < 4; ++jt) {
                float a0 = exp2f(fmaf(C1, sfT[jt][0], nm - cj[jt][0]));
                float a1 = exp2f(fmaf(C1, sfT[jt][1], nm - cj[jt][1]));
                float a2 = exp2f(fmaf(C1, sfT[jt][2], nm - cj[jt][2]));
                float a3 = exp2f(fmaf(C1, sfT[jt][3], nm - cj[jt][3]));
                fp16x2 lo = __builtin_amdgcn_cvt_pkrtz(a0, a1);
                fp16x2 hi = __builtin_amdgcn_cvt_pkrtz(a2, a3);
                const int base = (jt & 1) * 4;
                if (jt < 2) {
                    pf0[base + 0] = (_Float16)lo[0]; pf0[base + 1] = (_Float16)lo[1];
                    pf0[base + 2] = (_Float16)hi[0]; pf0[base + 3] = (_Float16)hi[1];
                } else {
                    pf1[base + 0] = (_Float16)lo[0]; pf1[base + 1] = (_Float16)lo[1];
                    pf1[base + 2] = (_Float16)hi[0]; pf1[base + 3] = (_Float16)hi[1];
                }
            }
        }
        // O^T[d][i] += sum_j V[d][j] * P[i][j]; l += sum_j P[i][j] (ones-A MFMA)
        __builtin_amdgcn_s_setprio(1);
        #pragma unroll
        for (int dt = 0; dt < 4; ++dt) {
            half8 v0 = *(const half8*)(vl + (dt * 16 + col) * 64 + ((0 * 4 + g) ^ c7) * 8);
            half8 v1 = *(const half8*)(vl + (dt * 16 + col) * 64 + ((1 * 4 + g) ^ c7) * 8);
            oaccT[dt] = __builtin_amdgcn_mfma_f32_16x16x32_f16(v0, pf0, oaccT[dt], 0, 0, 0);
            oaccT[dt] = __builtin_amdgcn_mfma_f32_16x16x32_f16(v1, pf1, oaccT[dt], 0, 0, 0);
        }
        lacc = __builtin_amdgcn_mfma_f32_16x16x32_f16(ones1, pf0, lacc, 0, 0, 0);
        lacc = __builtin_amdgcn_mfma_f32_16x16x32_f16(ones1, pf1, lacc, 0, 0, 0);
        __builtin_amdgcn_s_setprio(0);

        __syncthreads();   // staging of tile+1 complete; reads of tile done
        cb ^= 1;
    }

    // epilogue: l complete per lane (MFMA k-dim summed all j), normalize, store
    float* aob = AO + ((size_t)(bh >> 3) * DINNER + h * 64) * N_PIX;
    {
        float linv = 1.f / lacc[0];
        const int p = i0 + col;
        #pragma unroll
        for (int dt = 0; dt < 4; ++dt)
            #pragma unroll
            for (int r = 0; r < 4; ++r)
                aob[(size_t)(dt * 16 + 4 * g + r) * N_PIX + p] = oaccT[dt][r] * linv;
    }
}

// ---------------------------------------------------------------------------
// Kernel 4: output GEMM  out[o=256][p] = sum_c Wout[o][c] * AO[b][c][p]
// ---------------------------------------------------------------------------
__global__ __launch_bounds__(256) void outproj_kernel(
    const float* __restrict__ AO, const float* __restrict__ Wout,
    float* __restrict__ out) {
    const int pt = blockIdx.x, mt = blockIdx.y, b = blockIdx.z;
    const int p0 = pt * 64, m0 = mt * 64;
    __shared__ float As[16][68];
    __shared__ float Bs[16][68];
    const int t = threadIdx.x, tm = t >> 4, tn = t & 15;
    float acc[4][4] = {};
    for (int kt = 0; kt < DINNER; kt += 16) {
        __syncthreads();
        for (int e = t; e < 1024; e += 256) {
            int m = e >> 4, kk = e & 15;
            As[kk][m] = Wout[(size_t)(m0 + m) * DINNER + kt + kk];
        }
        for (int e = t; e < 1024; e += 256) {
            int kk = e >> 6, pp = e & 63;
            Bs[kk][pp] = AO[((size_t)b * DINNER + kt + kk) * N_PIX + p0 + pp];
        }
        __syncthreads();
        #pragma unroll
        for (int kk = 0; kk < 16; ++kk) {
            vf4 a = *(const vf4*)&As[kk][4 * tm];
            vf4 bb = *(const vf4*)&Bs[kk][4 * tn];
            #pragma unroll
            for (int r = 0; r < 4; ++r)
                #pragma unroll
                for (int c = 0; c < 4; ++c)
                    acc[r][c] = fmaf(a[r], bb[c], acc[r][c]);
        }
    }
    #pragma unroll
    for (int r = 0; r < 4; ++r) {
        vf4 o4 = {acc[r][0], acc[r][1], acc[r][2], acc[r][3]};
        *(vf4*)&out[((size_t)b * CDIM + m0 + 4 * tm + r) * N_PIX + p0 + 4 * tn] = o4;
    }
}

// ---------------------------------------------------------------------------
extern "C" void kernel_launch(void* const* d_in, const int* in_sizes, int n_in,
                              void* d_out, int out_size, void* d_ws, size_t ws_size,
                              hipStream_t stream) {
    const float* fmap   = (const float*)d_in[0];
    const float* gamma  = (const float*)d_in[1];
    const float* Wq     = (const float*)d_in[2];
    const float* Wv     = (const float*)d_in[3];
    const float* Wout   = (const float*)d_in[4];
    const float* nullkv = (const float*)d_in[5];
    float* out = (float*)d_out;

    char* wsb = (char*)d_ws;
    _Float16* Kst = (_Float16*)wsb;                          // 8 MB
    _Float16* Vst = (_Float16*)(wsb + (8u << 20));           // 8 MB
    // fmapT16 (4 MB) + Wg16 (0.5 MB) overlay the AO region: both are dead
    // before attn_kernel writes AO.
    _Float16* fmapT16 = (_Float16*)(wsb + (16u << 20));      // 4 MB
    _Float16* Wg16    = (_Float16*)(wsb + (20u << 20));      // 512 KB
    float*    AO  = (float*)(wsb + (16u << 20));             // 16 MB
    float*    cksq = (float*)(wsb + (32u << 20));            // 256 KB
    float*    rnorm = (float*)(wsb + (33u << 20));           // 32 KB

    rnorm_kernel<<<128, 256, 0, stream>>>(fmap, rnorm, fmapT16);
    wg16_kernel<<<256, 256, 0, stream>>>(Wq, Wv, gamma, Wg16);
    proj_mfma<<<dim3(64, 16, 2), 256, 0, stream>>>(fmapT16, Wg16, rnorm, Kst, Vst, cksq);
    attn_kernel<<<512, 512, 0, stream>>>(Kst, Vst, cksq, nullkv, AO);
    outproj_kernel<<<dim3(64, 4, 2), 256, 0, stream>>>(AO, Wout, out);
}

// Round 10
// 187.310 us; speedup vs baseline: 4.3698x; 1.3203x over previous
//
#include <hip/hip_runtime.h>
#include <math.h>
#include <stdint.h>

#define N_PIX 4096
#define CDIM 256
#define DINNER 512

typedef float vf4 __attribute__((ext_vector_type(4)));
typedef float f32x4 __attribute__((ext_vector_type(4)));
typedef _Float16 half8 __attribute__((ext_vector_type(8)));
typedef _Float16 half4v __attribute__((ext_vector_type(4)));
typedef __fp16 fp16x2 __attribute__((ext_vector_type(2)));

// log2(e) scalings: softmax done in exp2 domain
#define LOG2E 1.44269504f
#define CKSQ_SCALE 0.18033688f   /* 0.125 * log2e */
#define C1 0.36067376f           /* 0.25  * log2e */

// async global->LDS, 16B per lane, LDS dest = wave-uniform base + lane*16
#define GLOAD_LDS16(g, l)                                                  \
    __builtin_amdgcn_global_load_lds(                                      \
        (const __attribute__((address_space(1))) unsigned int*)(g),       \
        (__attribute__((address_space(3))) unsigned int*)(l), 16, 0, 0)

// ---------------------------------------------------------------------------
// Kernel 1: per-pixel channel L2 norm -> rnorm = sqrt(256)/max(||x||,1e-12),
// fused with fp16 transpose of fmap: fmapT16[b*4096+p][c] = fp16(fmap[b][c][p]).
// ---------------------------------------------------------------------------
__global__ __launch_bounds__(256) void rnorm_kernel(const float* __restrict__ fmap,
                                                    float* __restrict__ rnorm,
                                                    _Float16* __restrict__ fmapT16) {
    __shared__ float red[4][64];
    const int t = threadIdx.x;
    const int pl = t & 63;
    const int part = t >> 6;
    const int pix0 = blockIdx.x * 64;
    const int gp = pix0 + pl;
    const int b = gp >> 12, p = gp & 4095;
    const float* f = fmap + ((size_t)b * CDIM + part * 64) * N_PIX + p;
    _Float16* o16 = fmapT16 + (size_t)gp * CDIM + part * 64;
    float s = 0.f;
    #pragma unroll
    for (int c8 = 0; c8 < 64; c8 += 8) {
        half8 hv;
        #pragma unroll
        for (int e = 0; e < 8; ++e) {
            float x = f[(size_t)(c8 + e) * N_PIX];
            s = fmaf(x, x, s);
            hv[e] = (_Float16)x;
        }
        *(half8*)(o16 + c8) = hv;
    }
    red[part][pl] = s;
    __syncthreads();
    if (t < 64) {
        float tot = red[0][t] + red[1][t] + red[2][t] + red[3][t];
        rnorm[pix0 + t] = 16.0f / fmaxf(sqrtf(tot), 1e-12f);
    }
}

// ---------------------------------------------------------------------------
// Kernel 1b: Wg16[o][c] = fp16( (o<512 ? Wq[o] : Wv[o-512])[c] * gamma[c] )
// ---------------------------------------------------------------------------
__global__ __launch_bounds__(256) void wg16_kernel(
    const float* __restrict__ Wq, const float* __restrict__ Wv,
    const float* __restrict__ gamma, _Float16* __restrict__ Wg16) {
    const int t = threadIdx.x;
    const int o = blockIdx.x * 4 + (t >> 6);
    const int c = (t & 63) * 4;
    const float* W = (o < DINNER) ? (Wq + (size_t)o * CDIM)
                                  : (Wv + (size_t)(o - DINNER) * CDIM);
    vf4 wv = *(const vf4*)(W + c);
    vf4 gv = *(const vf4*)(gamma + c);
    half4v h = {(_Float16)(wv[0] * gv[0]), (_Float16)(wv[1] * gv[1]),
                (_Float16)(wv[2] * gv[2]), (_Float16)(wv[3] * gv[3])};
    *(half4v*)(Wg16 + (size_t)o * CDIM + c) = h;
}

// ---------------------------------------------------------------------------
// Kernel 1c: Wout16 = fp16(Wout)  (256 x 512, flat)
// ---------------------------------------------------------------------------
__global__ __launch_bounds__(256) void wout16_kernel(
    const float* __restrict__ Wout, _Float16* __restrict__ Wout16) {
    const int idx = (blockIdx.x * 256 + threadIdx.x) * 4;
    vf4 wv = *(const vf4*)(Wout + idx);
    half4v h = {(_Float16)wv[0], (_Float16)wv[1], (_Float16)wv[2], (_Float16)wv[3]};
    *(half4v*)(Wout16 + idx) = h;
}

// ---------------------------------------------------------------------------
// Kernel 2: fp16 MFMA projection GEMM (unchanged from round 9).
// ---------------------------------------------------------------------------
__global__ __launch_bounds__(256) void proj_mfma(
    const _Float16* __restrict__ fmapT16,  // [b*4096+p][256]
    const _Float16* __restrict__ Wg16,     // [1024][256]
    const float* __restrict__ rnorm,       // [8192]
    _Float16* __restrict__ Kst, _Float16* __restrict__ Vst,
    float* __restrict__ cksq) {
    const int pt = blockIdx.x;             // 64
    const int mt = blockIdx.y;             // 16 (0..7 Q, 8..15 V)
    const int b = blockIdx.z;              // 2
    const int m0 = mt * 64;
    const bool isQ = (m0 < DINNER);
    const int h = (m0 & 511) >> 6;
    const int bh = b * 8 + h;
    const int p0 = pt * 64;

    const int t = threadIdx.x;
    const int w = t >> 6;
    const int lane = t & 63;
    const int col = lane & 15;
    const int g = lane >> 4;
    const int p = p0 + w * 16 + col;       // this lane's pixel
    const int j = w * 16 + col;            // pixel within the 64-tile

    const _Float16* bbase = fmapT16 + ((size_t)b * N_PIX + p) * CDIM;
    const _Float16* abase = Wg16 + (size_t)m0 * CDIM;

    f32x4 acc[4] = {};
    #pragma unroll
    for (int ks = 0; ks < 8; ++ks) {
        half8 bf = *(const half8*)(bbase + ks * 32 + g * 8);
        #pragma unroll
        for (int ms = 0; ms < 4; ++ms) {
            half8 af = *(const half8*)(abase + (size_t)(ms * 16 + col) * CDIM + ks * 32 + g * 8);
            acc[ms] = __builtin_amdgcn_mfma_f32_16x16x32_f16(af, bf, acc[ms], 0, 0, 0);
        }
    }

    const float rn = rnorm[b * N_PIX + p];
    _Float16 qh[4][4];
    #pragma unroll
    for (int ms = 0; ms < 4; ++ms)
        #pragma unroll
        for (int r = 0; r < 4; ++r)
            qh[ms][r] = (_Float16)(acc[ms][r] * rn);

    if (isQ) {
        float qs = 0.f;
        #pragma unroll
        for (int ms = 0; ms < 4; ++ms)
            #pragma unroll
            for (int r = 0; r < 4; ++r) {
                float qv = (float)qh[ms][r];
                qs = fmaf(qv, qv, qs);
            }
        qs += __shfl_xor(qs, 16);
        qs += __shfl_xor(qs, 32);
        _Float16* kt2 = Kst + ((size_t)bh * 64 + pt) * 4096;
        #pragma unroll
        for (int ms = 0; ms < 4; ++ms) {
            half4v hv = {qh[ms][0], qh[ms][1], qh[ms][2], qh[ms][3]};
            *(half4v*)(kt2 + j * 64 + (((ms * 2 + (g >> 1)) ^ (j & 7)) * 8) + (g & 1) * 4) = hv;
        }
        if (g == 0)
            cksq[(size_t)bh * N_PIX + p] = CKSQ_SCALE * qs;
    } else {
        _Float16* vt2 = Vst + ((size_t)bh * 64 + pt) * 4096;
        const int svb = ((j >> 5) << 2) + ((j >> 2) & 3);
        const int off = ((j >> 4) & 1) * 4 + (j & 3);
        #pragma unroll
        for (int ms = 0; ms < 4; ++ms)
            #pragma unroll
            for (int r = 0; r < 4; ++r) {
                const int d = ms * 16 + 4 * g + r;
                vt2[d * 64 + ((svb ^ (d & 7)) << 3) + off] = qh[ms][r];
            }
    }
}

// ---------------------------------------------------------------------------
// Kernel 3: fp16 MFMA flash attention, swapped QK^T, 8 waves x 16 q-rows.
// 2 KV tiles per barrier; single fused LDS block so every ds_read is an
// immediate-offset off loop-invariant lane bases.  Epilogue writes fp16
// AO16[b*4096+p][512] (k-contiguous rows for the outproj MFMA B-operand).
// ---------------------------------------------------------------------------
__global__ __launch_bounds__(512, 4) void attn_kernel(
    const _Float16* __restrict__ Kst,  // [bh][64][4096] xor-slotted
    const _Float16* __restrict__ Vst,  // [bh][64][4096] xor-slotted
    const float* __restrict__ cksq,    // [bh][p] = 0.125*log2e*ksq
    const float* __restrict__ nullkv,  // [2][8][64] fp32
    _Float16* __restrict__ AO16)       // [b*4096+p][512]
{
    const int n = blockIdx.x;
    const int slot = n >> 3;
    const int bh = (n & 7) * 2 + (slot >> 5);   // XCD swizzle: 2 bh per XCD
    const int it = slot & 31;
    const int h = bh & 7;

    // [buf][K(t0),K(t1),V(t0),V(t1)][4096]
    __shared__ __align__(16) _Float16 kv_lds[2][4][4096];

    const int t = threadIdx.x;
    const int w = t >> 6;          // 0..7
    const int lane = t & 63;
    const int col = lane & 15;
    const int g = lane >> 4;
    const int c7 = col & 7;

    const _Float16* kbase = Kst + (size_t)bh * (64 * 4096);
    const _Float16* vbase = Vst + (size_t)bh * (64 * 4096);
    const float* ck = cksq + (size_t)bh * N_PIX;
    const int i0 = it * 128 + w * 16;

    // prologue: stage tiles 0,1 into buf 0 (wave w stages chunk w of each)
    GLOAD_LDS16(kbase + w * 512 + lane * 8, &kv_lds[0][0][w * 512]);
    GLOAD_LDS16(kbase + 4096 + w * 512 + lane * 8, &kv_lds[0][1][w * 512]);
    GLOAD_LDS16(vbase + w * 512 + lane * 8, &kv_lds[0][2][w * 512]);
    GLOAD_LDS16(vbase + 4096 + w * 512 + lane * 8, &kv_lds[0][3][w * 512]);

    // Q fragment (B-operand of S^T mfma) from global Kst: d = dk*32+g*8+e
    half8 qf[2];
    {
        const int i = i0 + col;
        #pragma unroll
        for (int dk = 0; dk < 2; ++dk)
            qf[dk] = *(const half8*)(kbase + (size_t)(i >> 6) * 4096 +
                                     (i & 63) * 64 + ((dk * 4 + g) ^ c7) * 8);
    }

    // null kv: per-lane nd for q-row = l&15 after g-group reduction
    float nd = 0.f, nkk = 0.f;
    #pragma unroll
    for (int dk = 0; dk < 2; ++dk) {
        const float* np = nullkv + h * 64 + dk * 32 + g * 8;
        #pragma unroll
        for (int e = 0; e < 8; ++e) {
            float nkval = np[e];
            nkk = fmaf(nkval, nkval, nkk);
            nd = fmaf((float)qf[dk][e], nkval, nd);
        }
    }
    nd += __shfl_xor(nd, 16); nd += __shfl_xor(nd, 32);
    nkk += __shfl_xor(nkk, 16); nkk += __shfl_xor(nkk, 32);

    // null V values at d = dt*16 + 4g + r (matches O^T D-layout)
    vf4 nv4[4];
    #pragma unroll
    for (int dt = 0; dt < 4; ++dt)
        nv4[dt] = *(const vf4*)(nullkv + DINNER + h * 64 + dt * 16 + 4 * g);

    float m_;
    f32x4 oaccT[4];
    f32x4 lacc;
    {
        float nsim = fmaf(0.25f, nd, -0.125f * nkk) * LOG2E;
        float ci = ck[i0 + col];
        m_ = fmaxf(ci, nsim);
        float wn = exp2f(nsim - m_);
        lacc = f32x4{wn, wn, wn, wn};
        #pragma unroll
        for (int dt = 0; dt < 4; ++dt)
            #pragma unroll
            for (int r = 0; r < 4; ++r)
                oaccT[dt][r] = wn * nv4[dt][r];
    }

    const half8 ones1 = {(_Float16)1.f, (_Float16)1.f, (_Float16)1.f, (_Float16)1.f,
                         (_Float16)1.f, (_Float16)1.f, (_Float16)1.f, (_Float16)1.f};
    const float nm = -m_;

    // one tile: S^T mfma -> exp2 softmax -> PV mfma + ones-l mfma
    auto do_tile = [&](const _Float16* kl, const _Float16* vl, int j0) {
        vf4 cj[4];
        #pragma unroll
        for (int jt = 0; jt < 4; ++jt)
            cj[jt] = *(const vf4*)&ck[j0 + jt * 16 + 4 * g];

        half8 kf[4][2];
        #pragma unroll
        for (int jt = 0; jt < 4; ++jt)
            #pragma unroll
            for (int dk = 0; dk < 2; ++dk)
                kf[jt][dk] = *(const half8*)(kl + (jt * 16 + col) * 64 +
                                             ((dk * 4 + g) ^ c7) * 8);
        f32x4 sfT[4];
        __builtin_amdgcn_s_setprio(1);
        #pragma unroll
        for (int jt = 0; jt < 4; ++jt) {
            sfT[jt] = f32x4{0.f, 0.f, 0.f, 0.f};
            sfT[jt] = __builtin_amdgcn_mfma_f32_16x16x32_f16(kf[jt][0], qf[0], sfT[jt], 0, 0, 0);
            sfT[jt] = __builtin_amdgcn_mfma_f32_16x16x32_f16(kf[jt][1], qf[1], sfT[jt], 0, 0, 0);
        }
        __builtin_amdgcn_s_setprio(0);

        half8 pf0, pf1;
        #pragma unroll
        for (int jt = 0; jt < 4; ++jt) {
            float a0 = exp2f(fmaf(C1, sfT[jt][0], nm - cj[jt][0]));
            float a1 = exp2f(fmaf(C1, sfT[jt][1], nm - cj[jt][1]));
            float a2 = exp2f(fmaf(C1, sfT[jt][2], nm - cj[jt][2]));
            float a3 = exp2f(fmaf(C1, sfT[jt][3], nm - cj[jt][3]));
            fp16x2 lo = __builtin_amdgcn_cvt_pkrtz(a0, a1);
            fp16x2 hi = __builtin_amdgcn_cvt_pkrtz(a2, a3);
            const int base = (jt & 1) * 4;
            if (jt < 2) {
                pf0[base + 0] = (_Float16)lo[0]; pf0[base + 1] = (_Float16)lo[1];
                pf0[base + 2] = (_Float16)hi[0]; pf0[base + 3] = (_Float16)hi[1];
            } else {
                pf1[base + 0] = (_Float16)lo[0]; pf1[base + 1] = (_Float16)lo[1];
                pf1[base + 2] = (_Float16)hi[0]; pf1[base + 3] = (_Float16)hi[1];
            }
        }
        __builtin_amdgcn_s_setprio(1);
        #pragma unroll
        for (int dt = 0; dt < 4; ++dt) {
            half8 v0 = *(const half8*)(vl + (dt * 16 + col) * 64 + ((0 * 4 + g) ^ c7) * 8);
            half8 v1 = *(const half8*)(vl + (dt * 16 + col) * 64 + ((1 * 4 + g) ^ c7) * 8);
            oaccT[dt] = __builtin_amdgcn_mfma_f32_16x16x32_f16(v0, pf0, oaccT[dt], 0, 0, 0);
            oaccT[dt] = __builtin_amdgcn_mfma_f32_16x16x32_f16(v1, pf1, oaccT[dt], 0, 0, 0);
        }
        lacc = __builtin_amdgcn_mfma_f32_16x16x32_f16(ones1, pf0, lacc, 0, 0, 0);
        lacc = __builtin_amdgcn_mfma_f32_16x16x32_f16(ones1, pf1, lacc, 0, 0, 0);
        __builtin_amdgcn_s_setprio(0);
    };

    __syncthreads();   // tiles 0,1 staged

    int cb = 0;
    #pragma unroll 1
    for (int jp = 0; jp < 32; ++jp) {
        if (jp < 31) {
            const _Float16* kt = kbase + (size_t)(jp * 2 + 2) * 4096;
            const _Float16* vt = vbase + (size_t)(jp * 2 + 2) * 4096;
            _Float16* dst = &kv_lds[cb ^ 1][0][0];
            GLOAD_LDS16(kt + w * 512 + lane * 8, dst + w * 512);
            GLOAD_LDS16(kt + 4096 + w * 512 + lane * 8, dst + 4096 + w * 512);
            GLOAD_LDS16(vt + w * 512 + lane * 8, dst + 8192 + w * 512);
            GLOAD_LDS16(vt + 4096 + w * 512 + lane * 8, dst + 12288 + w * 512);
        }
        do_tile(&kv_lds[cb][0][0], &kv_lds[cb][2][0], jp * 128);
        do_tile(&kv_lds[cb][1][0], &kv_lds[cb][3][0], jp * 128 + 64);
        __syncthreads();   // staging complete; reads of this buf done
        cb ^= 1;
    }

    // epilogue: l complete per lane, normalize, store fp16 AO16[p][c]
    {
        float linv = 1.f / lacc[0];
        const int p = i0 + col;
        _Float16* aop = AO16 + ((size_t)(bh >> 3) * N_PIX + p) * DINNER + (h << 6);
        #pragma unroll
        for (int dt = 0; dt < 4; ++dt) {
            half4v hv = {(_Float16)(oaccT[dt][0] * linv), (_Float16)(oaccT[dt][1] * linv),
                         (_Float16)(oaccT[dt][2] * linv), (_Float16)(oaccT[dt][3] * linv)};
            *(half4v*)(aop + dt * 16 + 4 * g) = hv;
        }
    }
}

// ---------------------------------------------------------------------------
// Kernel 4: fp16 MFMA output GEMM: out[b][o][p] = sum_c Wout16[o][c]*AO16[p][c]
// ---------------------------------------------------------------------------
__global__ __launch_bounds__(256) void outproj_mfma(
    const _Float16* __restrict__ AO16,    // [b*4096+p][512]
    const _Float16* __restrict__ Wout16,  // [256][512]
    float* __restrict__ out) {
    const int pt = blockIdx.x;   // 64
    const int mt = blockIdx.y;   // 4
    const int b = blockIdx.z;    // 2
    const int t = threadIdx.x;
    const int w = t >> 6, lane = t & 63, col = lane & 15, g = lane >> 4;
    const int p = pt * 64 + w * 16 + col;

    const _Float16* bbase = AO16 + ((size_t)b * N_PIX + p) * DINNER;
    const _Float16* abase = Wout16 + (size_t)(mt * 64) * DINNER;

    f32x4 acc[4] = {};
    #pragma unroll
    for (int ks = 0; ks < 16; ++ks) {
        half8 bf = *(const half8*)(bbase + ks * 32 + g * 8);
        #pragma unroll
        for (int ms = 0; ms < 4; ++ms) {
            half8 af = *(const half8*)(abase + (size_t)(ms * 16 + col) * DINNER + ks * 32 + g * 8);
            acc[ms] = __builtin_amdgcn_mfma_f32_16x16x32_f16(af, bf, acc[ms], 0, 0, 0);
        }
    }
    float* ob = out + ((size_t)b * CDIM + mt * 64) * N_PIX + p;
    #pragma unroll
    for (int ms = 0; ms < 4; ++ms)
        #pragma unroll
        for (int r = 0; r < 4; ++r)
            ob[(size_t)(ms * 16 + 4 * g + r) * N_PIX] = acc[ms][r];
}

// ---------------------------------------------------------------------------
extern "C" void kernel_launch(void* const* d_in, const int* in_sizes, int n_in,
                              void* d_out, int out_size, void* d_ws, size_t ws_size,
                              hipStream_t stream) {
    const float* fmap   = (const float*)d_in[0];
    const float* gamma  = (const float*)d_in[1];
    const float* Wq     = (const float*)d_in[2];
    const float* Wv     = (const float*)d_in[3];
    const float* Wout   = (const float*)d_in[4];
    const float* nullkv = (const float*)d_in[5];
    float* out = (float*)d_out;

    char* wsb = (char*)d_ws;
    _Float16* Kst = (_Float16*)wsb;                          // 8 MB
    _Float16* Vst = (_Float16*)(wsb + (8u << 20));           // 8 MB
    // fmapT16 (4 MB) + Wg16 (0.5 MB) overlay the AO16 region: both are dead
    // before attn_kernel writes AO16 (+16MB..+24MB).
    _Float16* fmapT16 = (_Float16*)(wsb + (16u << 20));      // 4 MB
    _Float16* Wg16    = (_Float16*)(wsb + (20u << 20));      // 512 KB
    _Float16* AO16    = (_Float16*)(wsb + (16u << 20));      // 8 MB
    _Float16* Wout16  = (_Float16*)(wsb + (31u << 20));      // 256 KB
    float*    cksq    = (float*)(wsb + (32u << 20));         // 256 KB
    float*    rnorm   = (float*)(wsb + (33u << 20));         // 32 KB

    rnorm_kernel<<<128, 256, 0, stream>>>(fmap, rnorm, fmapT16);
    wg16_kernel<<<256, 256, 0, stream>>>(Wq, Wv, gamma, Wg16);
    wout16_kernel<<<128, 256, 0, stream>>>(Wout, Wout16);
    proj_mfma<<<dim3(64, 16, 2), 256, 0, stream>>>(fmapT16, Wg16, rnorm, Kst, Vst, cksq);
    attn_kernel<<<512, 512, 0, stream>>>(Kst, Vst, cksq, nullkv, AO16);
    outproj_mfma<<<dim3(64, 4, 2), 256, 0, stream>>>(AO16, Wout16, out);
}

// Round 11
// 185.183 us; speedup vs baseline: 4.4199x; 1.0115x over previous
//
#include <hip/hip_runtime.h>
#include <math.h>
#include <stdint.h>

#define N_PIX 4096
#define CDIM 256
#define DINNER 512

typedef float vf4 __attribute__((ext_vector_type(4)));
typedef float f32x4 __attribute__((ext_vector_type(4)));
typedef _Float16 half8 __attribute__((ext_vector_type(8)));
typedef _Float16 half4v __attribute__((ext_vector_type(4)));
typedef __fp16 fp16x2 __attribute__((ext_vector_type(2)));
typedef uint32_t u32x4 __attribute__((ext_vector_type(4)));

// log2(e) scalings: softmax done in exp2 domain
#define LOG2E 1.44269504f
#define C1 0.36067376f           /* 0.25 * log2e */
// cksq stores -0.5*qsq; log2-domain diag max ci = -C1 * cksq

// async global->LDS, 16B per lane, LDS dest = wave-uniform base + lane*16
#define GLOAD_LDS16(g, l)                                                  \
    __builtin_amdgcn_global_load_lds(                                      \
        (const __attribute__((address_space(1))) unsigned int*)(g),       \
        (__attribute__((address_space(3))) unsigned int*)(l), 16, 0, 0)

// ---------------------------------------------------------------------------
// Kernel 1: per-pixel channel L2 norm -> rnorm = sqrt(256)/max(||x||,1e-12),
// fused with fp16 transpose of fmap: fmapT16[b*4096+p][c] = fp16(fmap[b][c][p]).
// ---------------------------------------------------------------------------
__global__ __launch_bounds__(256) void rnorm_kernel(const float* __restrict__ fmap,
                                                    float* __restrict__ rnorm,
                                                    _Float16* __restrict__ fmapT16) {
    __shared__ float red[4][64];
    const int t = threadIdx.x;
    const int pl = t & 63;
    const int part = t >> 6;
    const int pix0 = blockIdx.x * 64;
    const int gp = pix0 + pl;
    const int b = gp >> 12, p = gp & 4095;
    const float* f = fmap + ((size_t)b * CDIM + part * 64) * N_PIX + p;
    _Float16* o16 = fmapT16 + (size_t)gp * CDIM + part * 64;
    float s = 0.f;
    #pragma unroll
    for (int c8 = 0; c8 < 64; c8 += 8) {
        half8 hv;
        #pragma unroll
        for (int e = 0; e < 8; ++e) {
            float x = f[(size_t)(c8 + e) * N_PIX];
            s = fmaf(x, x, s);
            hv[e] = (_Float16)x;
        }
        *(half8*)(o16 + c8) = hv;
    }
    red[part][pl] = s;
    __syncthreads();
    if (t < 64) {
        float tot = red[0][t] + red[1][t] + red[2][t] + red[3][t];
        rnorm[pix0 + t] = 16.0f / fmaxf(sqrtf(tot), 1e-12f);
    }
}

// ---------------------------------------------------------------------------
// Kernel 1b: Wg16[o][c] = fp16( (o<512 ? Wq[o] : Wv[o-512])[c] * gamma[c] )
// ---------------------------------------------------------------------------
__global__ __launch_bounds__(256) void wg16_kernel(
    const float* __restrict__ Wq, const float* __restrict__ Wv,
    const float* __restrict__ gamma, _Float16* __restrict__ Wg16) {
    const int t = threadIdx.x;
    const int o = blockIdx.x * 4 + (t >> 6);
    const int c = (t & 63) * 4;
    const float* W = (o < DINNER) ? (Wq + (size_t)o * CDIM)
                                  : (Wv + (size_t)(o - DINNER) * CDIM);
    vf4 wv = *(const vf4*)(W + c);
    vf4 gv = *(const vf4*)(gamma + c);
    half4v h = {(_Float16)(wv[0] * gv[0]), (_Float16)(wv[1] * gv[1]),
                (_Float16)(wv[2] * gv[2]), (_Float16)(wv[3] * gv[3])};
    *(half4v*)(Wg16 + (size_t)o * CDIM + c) = h;
}

// ---------------------------------------------------------------------------
// Kernel 1c: Wout16 = fp16(Wout)  (256 x 512, flat)
// ---------------------------------------------------------------------------
__global__ __launch_bounds__(256) void wout16_kernel(
    const float* __restrict__ Wout, _Float16* __restrict__ Wout16) {
    const int idx = (blockIdx.x * 256 + threadIdx.x) * 4;
    vf4 wv = *(const vf4*)(Wout + idx);
    half4v h = {(_Float16)wv[0], (_Float16)wv[1], (_Float16)wv[2], (_Float16)wv[3]};
    *(half4v*)(Wout16 + idx) = h;
}

// ---------------------------------------------------------------------------
// Kernel 2: fp16 MFMA projection GEMM.  cksq now stores -0.5*qsq (exp2-domain
// accumulator-init form; diag max stays exact since qs comes from rounded q).
// ---------------------------------------------------------------------------
__global__ __launch_bounds__(256) void proj_mfma(
    const _Float16* __restrict__ fmapT16,  // [b*4096+p][256]
    const _Float16* __restrict__ Wg16,     // [1024][256]
    const float* __restrict__ rnorm,       // [8192]
    _Float16* __restrict__ Kst, _Float16* __restrict__ Vst,
    float* __restrict__ cksq) {
    const int pt = blockIdx.x;             // 64
    const int mt = blockIdx.y;             // 16 (0..7 Q, 8..15 V)
    const int b = blockIdx.z;              // 2
    const int m0 = mt * 64;
    const bool isQ = (m0 < DINNER);
    const int h = (m0 & 511) >> 6;
    const int bh = b * 8 + h;
    const int p0 = pt * 64;

    const int t = threadIdx.x;
    const int w = t >> 6;
    const int lane = t & 63;
    const int col = lane & 15;
    const int g = lane >> 4;
    const int p = p0 + w * 16 + col;       // this lane's pixel
    const int j = w * 16 + col;            // pixel within the 64-tile

    const _Float16* bbase = fmapT16 + ((size_t)b * N_PIX + p) * CDIM;
    const _Float16* abase = Wg16 + (size_t)m0 * CDIM;

    f32x4 acc[4] = {};
    #pragma unroll
    for (int ks = 0; ks < 8; ++ks) {
        half8 bf = *(const half8*)(bbase + ks * 32 + g * 8);
        #pragma unroll
        for (int ms = 0; ms < 4; ++ms) {
            half8 af = *(const half8*)(abase + (size_t)(ms * 16 + col) * CDIM + ks * 32 + g * 8);
            acc[ms] = __builtin_amdgcn_mfma_f32_16x16x32_f16(af, bf, acc[ms], 0, 0, 0);
        }
    }

    const float rn = rnorm[b * N_PIX + p];
    _Float16 qh[4][4];
    #pragma unroll
    for (int ms = 0; ms < 4; ++ms)
        #pragma unroll
        for (int r = 0; r < 4; ++r)
            qh[ms][r] = (_Float16)(acc[ms][r] * rn);

    if (isQ) {
        float qs = 0.f;
        #pragma unroll
        for (int ms = 0; ms < 4; ++ms)
            #pragma unroll
            for (int r = 0; r < 4; ++r) {
                float qv = (float)qh[ms][r];
                qs = fmaf(qv, qv, qs);
            }
        qs += __shfl_xor(qs, 16);
        qs += __shfl_xor(qs, 32);
        _Float16* kt2 = Kst + ((size_t)bh * 64 + pt) * 4096;
        #pragma unroll
        for (int ms = 0; ms < 4; ++ms) {
            half4v hv = {qh[ms][0], qh[ms][1], qh[ms][2], qh[ms][3]};
            *(half4v*)(kt2 + j * 64 + (((ms * 2 + (g >> 1)) ^ (j & 7)) * 8) + (g & 1) * 4) = hv;
        }
        if (g == 0)
            cksq[(size_t)bh * N_PIX + p] = -0.5f * qs;
    } else {
        _Float16* vt2 = Vst + ((size_t)bh * 64 + pt) * 4096;
        const int svb = ((j >> 5) << 2) + ((j >> 2) & 3);
        const int off = ((j >> 4) & 1) * 4 + (j & 3);
        #pragma unroll
        for (int ms = 0; ms < 4; ++ms)
            #pragma unroll
            for (int r = 0; r < 4; ++r) {
                const int d = ms * 16 + 4 * g + r;
                vt2[d * 64 + ((svb ^ (d & 7)) << 3) + off] = qh[ms][r];
            }
    }
}

// ---------------------------------------------------------------------------
// Kernel 3: fp16 MFMA flash attention, swapped QK^T, 8 waves x 16 q-rows.
// -cj folded into the S^T accumulator init (sfT_init = -0.5*ksq from LDS),
// so softmax is exp2(fma(C1, sfT, nm)) — no per-element sub, no zero-init.
// ---------------------------------------------------------------------------
__global__ __launch_bounds__(512, 4) void attn_kernel(
    const _Float16* __restrict__ Kst,  // [bh][64][4096] xor-slotted
    const _Float16* __restrict__ Vst,  // [bh][64][4096] xor-slotted
    const float* __restrict__ cksq,    // [bh][p] = -0.5*ksq
    const float* __restrict__ nullkv,  // [2][8][64] fp32
    _Float16* __restrict__ AO16)       // [b*4096+p][512]
{
    const int n = blockIdx.x;
    const int slot = n >> 3;
    const int bh = (n & 7) * 2 + (slot >> 5);   // XCD swizzle: 2 bh per XCD
    const int it = slot & 31;
    const int h = bh & 7;

    // [buf][K(t0),K(t1),V(t0),V(t1)][4096]
    __shared__ __align__(16) _Float16 kv_lds[2][4][4096];
    __shared__ __align__(16) float ksq_lds[4096];

    const int t = threadIdx.x;
    const int w = t >> 6;          // 0..7
    const int lane = t & 63;
    const int col = lane & 15;
    const int g = lane >> 4;
    const int c7 = col & 7;

    const _Float16* kbase = Kst + (size_t)bh * (64 * 4096);
    const _Float16* vbase = Vst + (size_t)bh * (64 * 4096);
    const float* ck = cksq + (size_t)bh * N_PIX;
    const int i0 = it * 128 + w * 16;

    // prologue: stage tiles 0,1 into buf 0 (wave w stages chunk w of each)
    GLOAD_LDS16(kbase + w * 512 + lane * 8, &kv_lds[0][0][w * 512]);
    GLOAD_LDS16(kbase + 4096 + w * 512 + lane * 8, &kv_lds[0][1][w * 512]);
    GLOAD_LDS16(vbase + w * 512 + lane * 8, &kv_lds[0][2][w * 512]);
    GLOAD_LDS16(vbase + 4096 + w * 512 + lane * 8, &kv_lds[0][3][w * 512]);
    // stage -0.5*ksq (accumulator init values) into LDS
    #pragma unroll
    for (int e = 0; e < 2; ++e)
        *(vf4*)&ksq_lds[t * 8 + e * 4] = *(const vf4*)&ck[t * 8 + e * 4];

    // Q fragment (B-operand of S^T mfma) from global Kst: d = dk*32+g*8+e
    half8 qf[2];
    {
        const int i = i0 + col;
        #pragma unroll
        for (int dk = 0; dk < 2; ++dk)
            qf[dk] = *(const half8*)(kbase + (size_t)(i >> 6) * 4096 +
                                     (i & 63) * 64 + ((dk * 4 + g) ^ c7) * 8);
    }

    // null kv: per-lane nd for q-row = l&15 after g-group reduction
    float nd = 0.f, nkk = 0.f;
    #pragma unroll
    for (int dk = 0; dk < 2; ++dk) {
        const float* np = nullkv + h * 64 + dk * 32 + g * 8;
        #pragma unroll
        for (int e = 0; e < 8; ++e) {
            float nkval = np[e];
            nkk = fmaf(nkval, nkval, nkk);
            nd = fmaf((float)qf[dk][e], nkval, nd);
        }
    }
    nd += __shfl_xor(nd, 16); nd += __shfl_xor(nd, 32);
    nkk += __shfl_xor(nkk, 16); nkk += __shfl_xor(nkk, 32);

    // null V values at d = dt*16 + 4g + r (matches O^T D-layout)
    vf4 nv4[4];
    #pragma unroll
    for (int dt = 0; dt < 4; ++dt)
        nv4[dt] = *(const vf4*)(nullkv + DINNER + h * 64 + dt * 16 + 4 * g);

    float m_;
    f32x4 oaccT[4];
    f32x4 lacc;
    {
        float nsim = fmaf(0.25f, nd, -0.125f * nkk) * LOG2E;
        float ci = -C1 * ck[i0 + col];        // log2-domain diag max
        m_ = fmaxf(ci, nsim);
        float wn = exp2f(nsim - m_);
        lacc = f32x4{wn, wn, wn, wn};
        #pragma unroll
        for (int dt = 0; dt < 4; ++dt)
            #pragma unroll
            for (int r = 0; r < 4; ++r)
                oaccT[dt][r] = wn * nv4[dt][r];
    }

    const half8 ones1 = {(_Float16)1.f, (_Float16)1.f, (_Float16)1.f, (_Float16)1.f,
                         (_Float16)1.f, (_Float16)1.f, (_Float16)1.f, (_Float16)1.f};
    const float nm = -m_;

    // one tile: S^T mfma (acc init = -0.5*ksq) -> exp2 -> PV mfma + ones-l mfma
    auto do_tile = [&](const _Float16* kl, const _Float16* vl, int j0) {
        f32x4 sfT[4];
        #pragma unroll
        for (int jt = 0; jt < 4; ++jt)
            sfT[jt] = *(const f32x4*)&ksq_lds[j0 + jt * 16 + 4 * g];

        half8 kf[4][2];
        #pragma unroll
        for (int jt = 0; jt < 4; ++jt)
            #pragma unroll
            for (int dk = 0; dk < 2; ++dk)
                kf[jt][dk] = *(const half8*)(kl + (jt * 16 + col) * 64 +
                                             ((dk * 4 + g) ^ c7) * 8);
        __builtin_amdgcn_s_setprio(1);
        #pragma unroll
        for (int jt = 0; jt < 4; ++jt) {
            sfT[jt] = __builtin_amdgcn_mfma_f32_16x16x32_f16(kf[jt][0], qf[0], sfT[jt], 0, 0, 0);
            sfT[jt] = __builtin_amdgcn_mfma_f32_16x16x32_f16(kf[jt][1], qf[1], sfT[jt], 0, 0, 0);
        }
        __builtin_amdgcn_s_setprio(0);

        uint32_t us[8];
        #pragma unroll
        for (int jt = 0; jt < 4; ++jt) {
            float a0 = exp2f(fmaf(C1, sfT[jt][0], nm));
            float a1 = exp2f(fmaf(C1, sfT[jt][1], nm));
            float a2 = exp2f(fmaf(C1, sfT[jt][2], nm));
            float a3 = exp2f(fmaf(C1, sfT[jt][3], nm));
            us[jt * 2]     = __builtin_bit_cast(uint32_t, __builtin_amdgcn_cvt_pkrtz(a0, a1));
            us[jt * 2 + 1] = __builtin_bit_cast(uint32_t, __builtin_amdgcn_cvt_pkrtz(a2, a3));
        }
        half8 pf0 = __builtin_bit_cast(half8, (u32x4){us[0], us[1], us[2], us[3]});
        half8 pf1 = __builtin_bit_cast(half8, (u32x4){us[4], us[5], us[6], us[7]});

        __builtin_amdgcn_s_setprio(1);
        #pragma unroll
        for (int dt = 0; dt < 4; ++dt) {
            half8 v0 = *(const half8*)(vl + (dt * 16 + col) * 64 + ((0 * 4 + g) ^ c7) * 8);
            half8 v1 = *(const half8*)(vl + (dt * 16 + col) * 64 + ((1 * 4 + g) ^ c7) * 8);
            oaccT[dt] = __builtin_amdgcn_mfma_f32_16x16x32_f16(v0, pf0, oaccT[dt], 0, 0, 0);
            oaccT[dt] = __builtin_amdgcn_mfma_f32_16x16x32_f16(v1, pf1, oaccT[dt], 0, 0, 0);
        }
        lacc = __builtin_amdgcn_mfma_f32_16x16x32_f16(ones1, pf0, lacc, 0, 0, 0);
        lacc = __builtin_amdgcn_mfma_f32_16x16x32_f16(ones1, pf1, lacc, 0, 0, 0);
        __builtin_amdgcn_s_setprio(0);
    };

    __syncthreads();   // tiles 0,1 + ksq staged

    int cb = 0;
    #pragma unroll 1
    for (int jp = 0; jp < 32; ++jp) {
        if (jp < 31) {
            const _Float16* kt = kbase + (size_t)(jp * 2 + 2) * 4096;
            const _Float16* vt = vbase + (size_t)(jp * 2 + 2) * 4096;
            _Float16* dst = &kv_lds[cb ^ 1][0][0];
            GLOAD_LDS16(kt + w * 512 + lane * 8, dst + w * 512);
            GLOAD_LDS16(kt + 4096 + w * 512 + lane * 8, dst + 4096 + w * 512);
            GLOAD_LDS16(vt + w * 512 + lane * 8, dst + 8192 + w * 512);
            GLOAD_LDS16(vt + 4096 + w * 512 + lane * 8, dst + 12288 + w * 512);
        }
        do_tile(&kv_lds[cb][0][0], &kv_lds[cb][2][0], jp * 128);
        do_tile(&kv_lds[cb][1][0], &kv_lds[cb][3][0], jp * 128 + 64);
        __syncthreads();   // staging complete; reads of this buf done
        cb ^= 1;
    }

    // epilogue: l complete per lane, normalize, store fp16 AO16[p][c]
    {
        float linv = 1.f / lacc[0];
        const int p = i0 + col;
        _Float16* aop = AO16 + ((size_t)(bh >> 3) * N_PIX + p) * DINNER + (h << 6);
        #pragma unroll
        for (int dt = 0; dt < 4; ++dt) {
            half4v hv = {(_Float16)(oaccT[dt][0] * linv), (_Float16)(oaccT[dt][1] * linv),
                         (_Float16)(oaccT[dt][2] * linv), (_Float16)(oaccT[dt][3] * linv)};
            *(half4v*)(aop + dt * 16 + 4 * g) = hv;
        }
    }
}

// ---------------------------------------------------------------------------
// Kernel 4: fp16 MFMA output GEMM: out[b][o][p] = sum_c Wout16[o][c]*AO16[p][c]
// ---------------------------------------------------------------------------
__global__ __launch_bounds__(256) void outproj_mfma(
    const _Float16* __restrict__ AO16,    // [b*4096+p][512]
    const _Float16* __restrict__ Wout16,  // [256][512]
    float* __restrict__ out) {
    const int pt = blockIdx.x;   // 64
    const int mt = blockIdx.y;   // 4
    const int b = blockIdx.z;    // 2
    const int t = threadIdx.x;
    const int w = t >> 6, lane = t & 63, col = lane & 15, g = lane >> 4;
    const int p = pt * 64 + w * 16 + col;

    const _Float16* bbase = AO16 + ((size_t)b * N_PIX + p) * DINNER;
    const _Float16* abase = Wout16 + (size_t)(mt * 64) * DINNER;

    f32x4 acc[4] = {};
    #pragma unroll
    for (int ks = 0; ks < 16; ++ks) {
        half8 bf = *(const half8*)(bbase + ks * 32 + g * 8);
        #pragma unroll
        for (int ms = 0; ms < 4; ++ms) {
            half8 af = *(const half8*)(abase + (size_t)(ms * 16 + col) * DINNER + ks * 32 + g * 8);
            acc[ms] = __builtin_amdgcn_mfma_f32_16x16x32_f16(af, bf, acc[ms], 0, 0, 0);
        }
    }
    float* ob = out + ((size_t)b * CDIM + mt * 64) * N_PIX + p;
    #pragma unroll
    for (int ms = 0; ms < 4; ++ms)
        #pragma unroll
        for (int r = 0; r < 4; ++r)
            ob[(size_t)(ms * 16 + 4 * g + r) * N_PIX] = acc[ms][r];
}

// ---------------------------------------------------------------------------
extern "C" void kernel_launch(void* const* d_in, const int* in_sizes, int n_in,
                              void* d_out, int out_size, void* d_ws, size_t ws_size,
                              hipStream_t stream) {
    const float* fmap   = (const float*)d_in[0];
    const float* gamma  = (const float*)d_in[1];
    const float* Wq     = (const float*)d_in[2];
    const float* Wv     = (const float*)d_in[3];
    const float* Wout   = (const float*)d_in[4];
    const float* nullkv = (const float*)d_in[5];
    float* out = (float*)d_out;

    char* wsb = (char*)d_ws;
    _Float16* Kst = (_Float16*)wsb;                          // 8 MB
    _Float16* Vst = (_Float16*)(wsb + (8u << 20));           // 8 MB
    // fmapT16 (4 MB) + Wg16 (0.5 MB) overlay the AO16 region: both are dead
    // before attn_kernel writes AO16 (+16MB..+24MB).
    _Float16* fmapT16 = (_Float16*)(wsb + (16u << 20));      // 4 MB
    _Float16* Wg16    = (_Float16*)(wsb + (20u << 20));      // 512 KB
    _Float16* AO16    = (_Float16*)(wsb + (16u << 20));      // 8 MB
    _Float16* Wout16  = (_Float16*)(wsb + (31u << 20));      // 256 KB
    float*    cksq    = (float*)(wsb + (32u << 20));         // 256 KB
    float*    rnorm   = (float*)(wsb + (33u << 20));         // 32 KB

    rnorm_kernel<<<128, 256, 0, stream>>>(fmap, rnorm, fmapT16);
    wg16_kernel<<<256, 256, 0, stream>>>(Wq, Wv, gamma, Wg16);
    wout16_kernel<<<128, 256, 0, stream>>>(Wout, Wout16);
    proj_mfma<<<dim3(64, 16, 2), 256, 0, stream>>>(fmapT16, Wg16, rnorm, Kst, Vst, cksq);
    attn_kernel<<<512, 512, 0, stream>>>(Kst, Vst, cksq, nullkv, AO16);
    outproj_mfma<<<dim3(64, 4, 2), 256, 0, stream>>>(AO16, Wout16, out);
}